// Round 1
// baseline (600.858 us; speedup 1.0000x reference)
//
#include <hip/hip_runtime.h>

// Problem constants
constexpr int B = 16;
constexpr int S = 1024;
constexpr int DM = 512;        // D_MODEL
constexpr int H = 6;           // HEADS
constexpr int DK = 8;          // D_K == D_V
constexpr int NJ = H * DK;     // 48 projection cols per matrix
constexpr int BS = B * S;      // 16384 rows

// exp2-domain scale: score = dot(q,k)/sqrt(8); p = exp(score) = exp2(score*log2e)
#define LOG2E 1.4426950408889634f
#define QSCALE (0.35355339059327373f * LOG2E)
#define MASKVAL (1e-9f * LOG2E)

// ---------------------------------------------------------------------------
// K0: mask int32 [B,S,S] -> bitmask [B*S, 16] uint64  (bit set => fill 1e-9)
// One wave per q-row; coalesced 256B loads + ballot.
__global__ __launch_bounds__(256) void maskbits_kernel(
    const int* __restrict__ mask, unsigned long long* __restrict__ bits) {
  int wave = threadIdx.x >> 6, lane = threadIdx.x & 63;
  int row = blockIdx.x * 4 + wave;            // [0, B*S)
  const int* mrow = mask + (size_t)row * S;
  unsigned long long* brow = bits + (size_t)row * 16;
#pragma unroll
  for (int c = 0; c < 16; c++) {
    int v = mrow[c * 64 + lane];
    unsigned long long bal = __ballot(v != 0);
    if (lane == 0) brow[c] = bal;
  }
}

// ---------------------------------------------------------------------------
// K1: projections. grid (BS/16, 3), block 256.
// Out layout [B,H,S,8]: out[((b*H+h)*S + s)*8 + d]
__global__ __launch_bounds__(256) void proj_kernel(
    const float* __restrict__ q_in, const float* __restrict__ k_in,
    const float* __restrict__ v_in,
    const float* __restrict__ Wq, const float* __restrict__ Wk,
    const float* __restrict__ Wv,
    const float* __restrict__ bq, const float* __restrict__ bk,
    const float* __restrict__ bv,
    float* __restrict__ Qo, float* __restrict__ Ko, float* __restrict__ Vo) {
  int m = blockIdx.y;
  const float* x    = (m == 0) ? q_in : (m == 1) ? k_in : v_in;
  const float* W    = (m == 0) ? Wq   : (m == 1) ? Wk   : Wv;
  const float* bias = (m == 0) ? bq   : (m == 1) ? bk   : bv;
  float* out        = (m == 0) ? Qo   : (m == 1) ? Ko   : Vo;

  __shared__ float xs[16 * DM];        // 32 KB: 16 input rows
  __shared__ float wt[64 * NJ];        // 12 KB: 64x48 W tile

  int t = threadIdx.x;
  int r0 = blockIdx.x * 16;

  // stage 16 rows of x
  const float4* xg = (const float4*)(x + (size_t)r0 * DM);
  float4* xs4 = (float4*)xs;
#pragma unroll
  for (int i = t; i < 16 * DM / 4; i += 256) xs4[i] = xg[i];

  int j = t & 63;        // col (active if < 48)
  int rq = t >> 6;       // row sub-group 0..3 (rows rq, rq+4, rq+8, rq+12)
  float acc[4] = {0.f, 0.f, 0.f, 0.f};

  for (int c0 = 0; c0 < DM; c0 += 64) {
    __syncthreads();
    // stage W tile rows c0..c0+63, all 48 cols (linear copy, coalesced)
#pragma unroll
    for (int i = t; i < 64 * NJ; i += 256) wt[i] = W[(size_t)c0 * NJ + i];
    __syncthreads();
    if (j < NJ) {
#pragma unroll
      for (int cc = 0; cc < 64; cc += 4) {
        float4 xa = *(const float4*)&xs[(rq + 0) * DM + c0 + cc];
        float4 xb = *(const float4*)&xs[(rq + 4) * DM + c0 + cc];
        float4 xc = *(const float4*)&xs[(rq + 8) * DM + c0 + cc];
        float4 xd = *(const float4*)&xs[(rq + 12) * DM + c0 + cc];
        float w0 = wt[(cc + 0) * NJ + j];
        float w1 = wt[(cc + 1) * NJ + j];
        float w2 = wt[(cc + 2) * NJ + j];
        float w3 = wt[(cc + 3) * NJ + j];
        acc[0] += xa.x * w0 + xa.y * w1 + xa.z * w2 + xa.w * w3;
        acc[1] += xb.x * w0 + xb.y * w1 + xb.z * w2 + xb.w * w3;
        acc[2] += xc.x * w0 + xc.y * w1 + xc.z * w2 + xc.w * w3;
        acc[3] += xd.x * w0 + xd.y * w1 + xd.z * w2 + xd.w * w3;
      }
    }
  }

  if (j < NJ) {
    float bj = bias[j];
    int h = j >> 3, d = j & 7;
#pragma unroll
    for (int i = 0; i < 4; i++) {
      int row = r0 + rq + 4 * i;
      int b = row >> 10, s = row & 1023;
      out[(((size_t)(b * H + h)) * S + s) * 8 + d] = acc[i] + bj;
    }
  }
}

// ---------------------------------------------------------------------------
// K2: attention. grid 1536 (= B*H*S/64), block 256 (4 waves).
// Each block: 64 queries (lane=query); wave w handles keys [w*256,(w+1)*256).
// Merge additive partials (no running max needed: scores bounded << 80).
__global__ __launch_bounds__(256) void attn_kernel(
    const float* __restrict__ Q, const float* __restrict__ K,
    const float* __restrict__ V, const unsigned long long* __restrict__ bits,
    float* __restrict__ A) {
  int bh = blockIdx.x >> 4;          // 0..95
  int qt = blockIdx.x & 15;
  int b = bh / H, h = bh % H;
  int wave = threadIdx.x >> 6, lane = threadIdx.x & 63;
  int q = qt * 64 + lane;

  const float* Qp = Q + ((size_t)bh * S + q) * 8;
  float4 q0 = *(const float4*)Qp;
  float4 q1 = *(const float4*)(Qp + 4);
  q0.x *= QSCALE; q0.y *= QSCALE; q0.z *= QSCALE; q0.w *= QSCALE;
  q1.x *= QSCALE; q1.y *= QSCALE; q1.z *= QSCALE; q1.w *= QSCALE;

  const unsigned long long* bp = bits + ((size_t)(b * S + q)) * 16;
  const float* Kp = K + (size_t)bh * S * 8;
  const float* Vp = V + (size_t)bh * S * 8;

  float4 accA = {0.f, 0.f, 0.f, 0.f};
  float4 accB = {0.f, 0.f, 0.f, 0.f};
  float denom = 0.f;

  int j0 = wave * 256;
#pragma unroll 1
  for (int g = 0; g < 4; g++) {
    int jg = j0 + g * 64;
    unsigned long long mb = bp[jg >> 6];
#pragma unroll 4
    for (int cc = 0; cc < 64; cc += 4) {
      int j = jg + cc;
      const float4* kp4 = (const float4*)(Kp + (size_t)j * 8);
      float4 k0a = kp4[0], k0b = kp4[1];
      float4 k1a = kp4[2], k1b = kp4[3];
      float4 k2a = kp4[4], k2b = kp4[5];
      float4 k3a = kp4[6], k3b = kp4[7];

      float s0 = q0.x * k0a.x + q0.y * k0a.y + q0.z * k0a.z + q0.w * k0a.w +
                 q1.x * k0b.x + q1.y * k0b.y + q1.z * k0b.z + q1.w * k0b.w;
      float s1 = q0.x * k1a.x + q0.y * k1a.y + q0.z * k1a.z + q0.w * k1a.w +
                 q1.x * k1b.x + q1.y * k1b.y + q1.z * k1b.z + q1.w * k1b.w;
      float s2 = q0.x * k2a.x + q0.y * k2a.y + q0.z * k2a.z + q0.w * k2a.w +
                 q1.x * k2b.x + q1.y * k2b.y + q1.z * k2b.z + q1.w * k2b.w;
      float s3 = q0.x * k3a.x + q0.y * k3a.y + q0.z * k3a.z + q0.w * k3a.w +
                 q1.x * k3b.x + q1.y * k3b.y + q1.z * k3b.z + q1.w * k3b.w;

      s0 = ((mb >> (cc + 0)) & 1ull) ? MASKVAL : s0;
      s1 = ((mb >> (cc + 1)) & 1ull) ? MASKVAL : s1;
      s2 = ((mb >> (cc + 2)) & 1ull) ? MASKVAL : s2;
      s3 = ((mb >> (cc + 3)) & 1ull) ? MASKVAL : s3;

      float p0 = exp2f(fminf(s0, 115.f));
      float p1 = exp2f(fminf(s1, 115.f));
      float p2 = exp2f(fminf(s2, 115.f));
      float p3 = exp2f(fminf(s3, 115.f));
      denom += (p0 + p1) + (p2 + p3);

      const float4* vp4 = (const float4*)(Vp + (size_t)j * 8);
      float4 v0a = vp4[0], v0b = vp4[1];
      float4 v1a = vp4[2], v1b = vp4[3];
      float4 v2a = vp4[4], v2b = vp4[5];
      float4 v3a = vp4[6], v3b = vp4[7];

      accA.x += p0 * v0a.x + p1 * v1a.x + p2 * v2a.x + p3 * v3a.x;
      accA.y += p0 * v0a.y + p1 * v1a.y + p2 * v2a.y + p3 * v3a.y;
      accA.z += p0 * v0a.z + p1 * v1a.z + p2 * v2a.z + p3 * v3a.z;
      accA.w += p0 * v0a.w + p1 * v1a.w + p2 * v2a.w + p3 * v3a.w;
      accB.x += p0 * v0b.x + p1 * v1b.x + p2 * v2b.x + p3 * v3b.x;
      accB.y += p0 * v0b.y + p1 * v1b.y + p2 * v2b.y + p3 * v3b.y;
      accB.z += p0 * v0b.z + p1 * v1b.z + p2 * v2b.z + p3 * v3b.z;
      accB.w += p0 * v0b.w + p1 * v1b.w + p2 * v2b.w + p3 * v3b.w;
    }
  }

  // merge the 4 key-split partials (pure sums)
  __shared__ float pd[4][64];
  __shared__ float4 pa[4][64];
  __shared__ float4 pb[4][64];
  pd[wave][lane] = denom;
  pa[wave][lane] = accA;
  pb[wave][lane] = accB;
  __syncthreads();
  if (wave == 0) {
#pragma unroll
    for (int w = 1; w < 4; w++) {
      denom += pd[w][lane];
      float4 ta = pa[w][lane], tb = pb[w][lane];
      accA.x += ta.x; accA.y += ta.y; accA.z += ta.z; accA.w += ta.w;
      accB.x += tb.x; accB.y += tb.y; accB.z += tb.z; accB.w += tb.w;
    }
    float inv = 1.f / denom;
    accA.x *= inv; accA.y *= inv; accA.z *= inv; accA.w *= inv;
    accB.x *= inv; accB.y *= inv; accB.z *= inv; accB.w *= inv;
    // A[b, s=q, h*8+d]
    float* Ap = A + ((size_t)(b * S + q)) * NJ + h * 8;
    *(float4*)Ap = accA;
    *(float4*)(Ap + 4) = accB;
  }
}

// ---------------------------------------------------------------------------
// K3: out = A@Wo + bo + residual, then LayerNorm. grid BS/8, block 256.
__global__ __launch_bounds__(256) void out_ln_kernel(
    const float* __restrict__ A, const float* __restrict__ Wo,
    const float* __restrict__ bo, const float* __restrict__ qin,
    const float* __restrict__ lnw, const float* __restrict__ lnb,
    float* __restrict__ out) {
  int r0 = blockIdx.x * 8;
  int t = threadIdx.x;
  __shared__ float As[8 * NJ];
#pragma unroll
  for (int i = t; i < 8 * NJ; i += 256) As[i] = A[(size_t)r0 * NJ + i];
  __syncthreads();

  int c0 = t, c1 = t + 256;
  float acc0[8], acc1[8];
#pragma unroll
  for (int r = 0; r < 8; r++) { acc0[r] = 0.f; acc1[r] = 0.f; }

#pragma unroll 4
  for (int j = 0; j < NJ; j++) {
    float w0 = Wo[(size_t)j * DM + c0];
    float w1 = Wo[(size_t)j * DM + c1];
#pragma unroll
    for (int r = 0; r < 8; r++) {
      float a = As[r * NJ + j];
      acc0[r] += a * w0;
      acc1[r] += a * w1;
    }
  }

  float b0 = bo[c0], b1 = bo[c1];
  float y0[8], y1[8], ssum[8], sq[8];
#pragma unroll
  for (int r = 0; r < 8; r++) {
    y0[r] = acc0[r] + b0 + qin[(size_t)(r0 + r) * DM + c0];
    y1[r] = acc1[r] + b1 + qin[(size_t)(r0 + r) * DM + c1];
    ssum[r] = y0[r] + y1[r];
    sq[r] = y0[r] * y0[r] + y1[r] * y1[r];
  }

  int wave = t >> 6, lane = t & 63;
  __shared__ float reds[4][8], redq[4][8];
#pragma unroll
  for (int r = 0; r < 8; r++) {
    float s = ssum[r], qq = sq[r];
#pragma unroll
    for (int off = 32; off > 0; off >>= 1) {
      s += __shfl_xor(s, off, 64);
      qq += __shfl_xor(qq, off, 64);
    }
    if (lane == 0) { reds[wave][r] = s; redq[wave][r] = qq; }
  }
  __syncthreads();

  float lw0 = lnw[c0], lw1 = lnw[c1], lb0 = lnb[c0], lb1 = lnb[c1];
#pragma unroll
  for (int r = 0; r < 8; r++) {
    float s = (reds[0][r] + reds[1][r]) + (reds[2][r] + reds[3][r]);
    float qq = (redq[0][r] + redq[1][r]) + (redq[2][r] + redq[3][r]);
    float mu = s * (1.f / 512.f);
    float var = qq * (1.f / 512.f) - mu * mu;
    float rstd = rsqrtf(var + 1e-5f);
    out[(size_t)(r0 + r) * DM + c0] = (y0[r] - mu) * rstd * lw0 + lb0;
    out[(size_t)(r0 + r) * DM + c1] = (y1[r] - mu) * rstd * lw1 + lb1;
  }
}

// ---------------------------------------------------------------------------
extern "C" void kernel_launch(void* const* d_in, const int* in_sizes, int n_in,
                              void* d_out, int out_size, void* d_ws,
                              size_t ws_size, hipStream_t stream) {
  const float* q_in = (const float*)d_in[0];
  const float* k_in = (const float*)d_in[1];
  const float* v_in = (const float*)d_in[2];
  const int* mask = (const int*)d_in[3];
  const float* Wq = (const float*)d_in[4];
  const float* bq = (const float*)d_in[5];
  const float* Wk = (const float*)d_in[6];
  const float* bk = (const float*)d_in[7];
  const float* Wv = (const float*)d_in[8];
  const float* bv = (const float*)d_in[9];
  const float* Wo = (const float*)d_in[10];
  const float* bo = (const float*)d_in[11];
  const float* lnw = (const float*)d_in[12];
  const float* lnb = (const float*)d_in[13];
  float* out = (float*)d_out;

  float* ws = (float*)d_ws;
  constexpr size_t QKV = (size_t)B * H * S * DK;  // 786432 floats each
  float* Qw = ws;
  float* Kw = ws + QKV;
  float* Vw = ws + 2 * QKV;
  float* Aw = ws + 3 * QKV;                        // [B*S, 48]
  unsigned long long* bits = (unsigned long long*)(ws + 4 * QKV);

  maskbits_kernel<<<BS / 4, 256, 0, stream>>>(mask, bits);
  proj_kernel<<<dim3(BS / 16, 3), 256, 0, stream>>>(
      q_in, k_in, v_in, Wq, Wk, Wv, bq, bk, bv, Qw, Kw, Vw);
  attn_kernel<<<(B * H * S) / 64, 256, 0, stream>>>(Qw, Kw, Vw, bits, Aw);
  out_ln_kernel<<<BS / 8, 256, 0, stream>>>(Aw, Wo, bo, q_in, lnw, lnb, out);
}

// Round 2
// 486.870 us; speedup vs baseline: 1.2341x; 1.2341x over previous
//
#include <hip/hip_runtime.h>

// Problem constants
constexpr int B = 16;
constexpr int S = 1024;
constexpr int DM = 512;        // D_MODEL
constexpr int H = 6;           // HEADS
constexpr int DK = 8;          // D_K == D_V
constexpr int NJ = H * DK;     // 48 projection cols per matrix
constexpr int BS = B * S;      // 16384 rows

typedef __attribute__((ext_vector_type(8))) short bf16x8;
typedef __attribute__((ext_vector_type(4))) float floatx4;

// exp2-domain scale: score = dot(q,k)/sqrt(8); p = exp(score) = exp2(score*log2e)
#define LOG2E 1.4426950408889634f
#define QSCALE (0.35355339059327373f * LOG2E)
#define MASKVAL (1e-9f * LOG2E)

__device__ inline ushort f2bf(float f) {
  unsigned int u = __builtin_bit_cast(unsigned int, f);
  return (ushort)((u + 0x7FFFu + ((u >> 16) & 1u)) >> 16);
}

// ---------------------------------------------------------------------------
// K0: mask int32 [B,S,S] -> bitmask [B*S, 16] uint64  (bit set => fill 1e-9)
__global__ __launch_bounds__(256) void maskbits_kernel(
    const int* __restrict__ mask, unsigned long long* __restrict__ bits) {
  int wave = threadIdx.x >> 6, lane = threadIdx.x & 63;
  int row = blockIdx.x * 4 + wave;            // [0, B*S)
  const int* mrow = mask + (size_t)row * S;
  unsigned long long* brow = bits + (size_t)row * 16;
#pragma unroll
  for (int c = 0; c < 16; c++) {
    int v = mrow[c * 64 + lane];
    unsigned long long bal = __ballot(v != 0);
    if (lane == 0) brow[c] = bal;
  }
}

// ---------------------------------------------------------------------------
// K0b: W prep — convert Wq/Wk/Wv fp32 [512][48] -> bf16 transposed [3][48][512]
__global__ __launch_bounds__(256) void wprep_kernel(
    const float* __restrict__ Wq, const float* __restrict__ Wk,
    const float* __restrict__ Wv, ushort* __restrict__ Wt) {
  int m = blockIdx.x;
  const float* W = (m == 0) ? Wq : (m == 1) ? Wk : Wv;
  ushort* dst = Wt + (size_t)m * NJ * DM;
  for (int e = threadIdx.x; e < DM * NJ; e += 256) {
    int k = e / NJ, n = e - k * NJ;
    dst[n * DM + k] = f2bf(W[e]);
  }
}

// ---------------------------------------------------------------------------
// K1: projections via bf16 MFMA. grid (BS/64, 3), block 256 (4 waves).
// Each block: 64 rows x 48 cols; wave w owns rows w*16..w*16+15, 3 N-tiles.
// K split in 2 phases of 256 (LDS: X 64x264 bf16 + W 48x264 bf16 = 58 KB).
// Out layout [B,H,S,8]: out[((b*H+h)*S + s)*8 + d]
__global__ __launch_bounds__(256) void proj_kernel(
    const float* __restrict__ q_in, const float* __restrict__ k_in,
    const float* __restrict__ v_in, const ushort* __restrict__ Wt,
    const float* __restrict__ bq, const float* __restrict__ bk,
    const float* __restrict__ bv,
    float* __restrict__ Qo, float* __restrict__ Ko, float* __restrict__ Vo) {
  int m = blockIdx.y;
  const float* x    = (m == 0) ? q_in : (m == 1) ? k_in : v_in;
  const float* bias = (m == 0) ? bq   : (m == 1) ? bk   : bv;
  float* out        = (m == 0) ? Qo   : (m == 1) ? Ko   : Vo;
  const ushort* Wg  = Wt + (size_t)m * NJ * DM;

  constexpr int LDK = 264;   // padded bf16 row stride (breaks 512-stride banks)
  __shared__ ushort Xs[64 * LDK];   // 33.8 KB
  __shared__ ushort Ws[NJ * LDK];   // 25.3 KB

  int t = threadIdx.x;
  int r0 = blockIdx.x * 64;
  int wave = t >> 6, lane = t & 63;
  int mrow = lane & 15, quad = lane >> 4;

  floatx4 acc0 = {0.f, 0.f, 0.f, 0.f};
  floatx4 acc1 = {0.f, 0.f, 0.f, 0.f};
  floatx4 acc2 = {0.f, 0.f, 0.f, 0.f};

#pragma unroll 1
  for (int p = 0; p < 2; p++) {
    int k0 = p * 256;
    __syncthreads();   // prior-phase reads done before restage
    // stage X: 64 rows x 256 k, fp32 -> bf16 (coalesced float4 reads)
#pragma unroll
    for (int i = 0; i < 16; i++) {
      int f = t + i * 256;          // float4 index among 4096
      int r = f >> 6;               // 64 float4 per row
      int c = (f & 63) * 4;
      float4 g = *(const float4*)&x[(size_t)(r0 + r) * DM + k0 + c];
      ushort4 h = {f2bf(g.x), f2bf(g.y), f2bf(g.z), f2bf(g.w)};
      *(ushort4*)&Xs[r * LDK + c] = h;
    }
    // stage W tile: 48 rows x 256 k (bf16 ushort4 copies)
#pragma unroll
    for (int i = 0; i < 12; i++) {
      int f = t + i * 256;          // ushort4 index among 3072
      int n = f >> 6;
      int c = (f & 63) * 4;
      *(ushort4*)&Ws[n * LDK + c] = *(const ushort4*)&Wg[(size_t)n * DM + k0 + c];
    }
    __syncthreads();
#pragma unroll
    for (int kc = 0; kc < 8; kc++) {
      int koff = kc * 32 + quad * 8;
      bf16x8 a  = *(const bf16x8*)&Xs[(wave * 16 + mrow) * LDK + koff];
      bf16x8 b0 = *(const bf16x8*)&Ws[(0  + mrow) * LDK + koff];
      bf16x8 b1 = *(const bf16x8*)&Ws[(16 + mrow) * LDK + koff];
      bf16x8 b2 = *(const bf16x8*)&Ws[(32 + mrow) * LDK + koff];
      acc0 = __builtin_amdgcn_mfma_f32_16x16x32_bf16(a, b0, acc0, 0, 0, 0);
      acc1 = __builtin_amdgcn_mfma_f32_16x16x32_bf16(a, b1, acc1, 0, 0, 0);
      acc2 = __builtin_amdgcn_mfma_f32_16x16x32_bf16(a, b2, acc2, 0, 0, 0);
    }
  }

  // epilogue: C/D layout col=lane&15, row=quad*4+reg
  int baseR = r0 + wave * 16 + quad * 4;
#pragma unroll
  for (int j = 0; j < 3; j++) {
    floatx4 a = (j == 0) ? acc0 : (j == 1) ? acc1 : acc2;
    int n = j * 16 + mrow;
    float bn = bias[n];
    int h = n >> 3, d = n & 7;
#pragma unroll
    for (int r = 0; r < 4; r++) {
      int R = baseR + r;
      int b = R >> 10, s = R & 1023;
      out[(((size_t)(b * H + h)) * S + s) * 8 + d] = a[r] + bn;
    }
  }
}

// ---------------------------------------------------------------------------
// K2: attention. grid 1536 (= B*H*S/64), block 256 (4 waves).
__global__ __launch_bounds__(256) void attn_kernel(
    const float* __restrict__ Q, const float* __restrict__ K,
    const float* __restrict__ V, const unsigned long long* __restrict__ bits,
    float* __restrict__ A) {
  int bh = blockIdx.x >> 4;          // 0..95
  int qt = blockIdx.x & 15;
  int b = bh / H, h = bh % H;
  int wave = threadIdx.x >> 6, lane = threadIdx.x & 63;
  int q = qt * 64 + lane;

  const float* Qp = Q + ((size_t)bh * S + q) * 8;
  float4 q0 = *(const float4*)Qp;
  float4 q1 = *(const float4*)(Qp + 4);
  q0.x *= QSCALE; q0.y *= QSCALE; q0.z *= QSCALE; q0.w *= QSCALE;
  q1.x *= QSCALE; q1.y *= QSCALE; q1.z *= QSCALE; q1.w *= QSCALE;

  const unsigned long long* bp = bits + ((size_t)(b * S + q)) * 16;
  const float* Kp = K + (size_t)bh * S * 8;
  const float* Vp = V + (size_t)bh * S * 8;

  float4 accA = {0.f, 0.f, 0.f, 0.f};
  float4 accB = {0.f, 0.f, 0.f, 0.f};
  float denom = 0.f;

  int j0 = wave * 256;
#pragma unroll 1
  for (int g = 0; g < 4; g++) {
    int jg = j0 + g * 64;
    unsigned long long mb = bp[jg >> 6];
#pragma unroll 4
    for (int cc = 0; cc < 64; cc += 4) {
      int j = jg + cc;
      const float4* kp4 = (const float4*)(Kp + (size_t)j * 8);
      float4 k0a = kp4[0], k0b = kp4[1];
      float4 k1a = kp4[2], k1b = kp4[3];
      float4 k2a = kp4[4], k2b = kp4[5];
      float4 k3a = kp4[6], k3b = kp4[7];

      float s0 = q0.x * k0a.x + q0.y * k0a.y + q0.z * k0a.z + q0.w * k0a.w +
                 q1.x * k0b.x + q1.y * k0b.y + q1.z * k0b.z + q1.w * k0b.w;
      float s1 = q0.x * k1a.x + q0.y * k1a.y + q0.z * k1a.z + q0.w * k1a.w +
                 q1.x * k1b.x + q1.y * k1b.y + q1.z * k1b.z + q1.w * k1b.w;
      float s2 = q0.x * k2a.x + q0.y * k2a.y + q0.z * k2a.z + q0.w * k2a.w +
                 q1.x * k2b.x + q1.y * k2b.y + q1.z * k2b.z + q1.w * k2b.w;
      float s3 = q0.x * k3a.x + q0.y * k3a.y + q0.z * k3a.z + q0.w * k3a.w +
                 q1.x * k3b.x + q1.y * k3b.y + q1.z * k3b.z + q1.w * k3b.w;

      s0 = ((mb >> (cc + 0)) & 1ull) ? MASKVAL : s0;
      s1 = ((mb >> (cc + 1)) & 1ull) ? MASKVAL : s1;
      s2 = ((mb >> (cc + 2)) & 1ull) ? MASKVAL : s2;
      s3 = ((mb >> (cc + 3)) & 1ull) ? MASKVAL : s3;

      float p0 = exp2f(fminf(s0, 115.f));
      float p1 = exp2f(fminf(s1, 115.f));
      float p2 = exp2f(fminf(s2, 115.f));
      float p3 = exp2f(fminf(s3, 115.f));
      denom += (p0 + p1) + (p2 + p3);

      const float4* vp4 = (const float4*)(Vp + (size_t)j * 8);
      float4 v0a = vp4[0], v0b = vp4[1];
      float4 v1a = vp4[2], v1b = vp4[3];
      float4 v2a = vp4[4], v2b = vp4[5];
      float4 v3a = vp4[6], v3b = vp4[7];

      accA.x += p0 * v0a.x + p1 * v1a.x + p2 * v2a.x + p3 * v3a.x;
      accA.y += p0 * v0a.y + p1 * v1a.y + p2 * v2a.y + p3 * v3a.y;
      accA.z += p0 * v0a.z + p1 * v1a.z + p2 * v2a.z + p3 * v3a.z;
      accA.w += p0 * v0a.w + p1 * v1a.w + p2 * v2a.w + p3 * v3a.w;
      accB.x += p0 * v0b.x + p1 * v1b.x + p2 * v2b.x + p3 * v3b.x;
      accB.y += p0 * v0b.y + p1 * v1b.y + p2 * v2b.y + p3 * v3b.y;
      accB.z += p0 * v0b.z + p1 * v1b.z + p2 * v2b.z + p3 * v3b.z;
      accB.w += p0 * v0b.w + p1 * v1b.w + p2 * v2b.w + p3 * v3b.w;
    }
  }

  // merge the 4 key-split partials (pure sums)
  __shared__ float pd[4][64];
  __shared__ float4 pa[4][64];
  __shared__ float4 pb[4][64];
  pd[wave][lane] = denom;
  pa[wave][lane] = accA;
  pb[wave][lane] = accB;
  __syncthreads();
  if (wave == 0) {
#pragma unroll
    for (int w = 1; w < 4; w++) {
      denom += pd[w][lane];
      float4 ta = pa[w][lane], tb = pb[w][lane];
      accA.x += ta.x; accA.y += ta.y; accA.z += ta.z; accA.w += ta.w;
      accB.x += tb.x; accB.y += tb.y; accB.z += tb.z; accB.w += tb.w;
    }
    float inv = 1.f / denom;
    accA.x *= inv; accA.y *= inv; accA.z *= inv; accA.w *= inv;
    accB.x *= inv; accB.y *= inv; accB.z *= inv; accB.w *= inv;
    float* Ap = A + ((size_t)(b * S + q)) * NJ + h * 8;
    *(float4*)Ap = accA;
    *(float4*)(Ap + 4) = accB;
  }
}

// ---------------------------------------------------------------------------
// K3: out = A@Wo + bo + residual, then LayerNorm. grid BS/8, block 256.
__global__ __launch_bounds__(256) void out_ln_kernel(
    const float* __restrict__ A, const float* __restrict__ Wo,
    const float* __restrict__ bo, const float* __restrict__ qin,
    const float* __restrict__ lnw, const float* __restrict__ lnb,
    float* __restrict__ out) {
  int r0 = blockIdx.x * 8;
  int t = threadIdx.x;
  __shared__ float As[8 * NJ];
#pragma unroll
  for (int i = t; i < 8 * NJ; i += 256) As[i] = A[(size_t)r0 * NJ + i];
  __syncthreads();

  int c0 = t, c1 = t + 256;
  float acc0[8], acc1[8];
#pragma unroll
  for (int r = 0; r < 8; r++) { acc0[r] = 0.f; acc1[r] = 0.f; }

#pragma unroll 4
  for (int j = 0; j < NJ; j++) {
    float w0 = Wo[(size_t)j * DM + c0];
    float w1 = Wo[(size_t)j * DM + c1];
#pragma unroll
    for (int r = 0; r < 8; r++) {
      float a = As[r * NJ + j];
      acc0[r] += a * w0;
      acc1[r] += a * w1;
    }
  }

  float b0 = bo[c0], b1 = bo[c1];
  float y0[8], y1[8], ssum[8], sq[8];
#pragma unroll
  for (int r = 0; r < 8; r++) {
    y0[r] = acc0[r] + b0 + qin[(size_t)(r0 + r) * DM + c0];
    y1[r] = acc1[r] + b1 + qin[(size_t)(r0 + r) * DM + c1];
    ssum[r] = y0[r] + y1[r];
    sq[r] = y0[r] * y0[r] + y1[r] * y1[r];
  }

  int wave = t >> 6, lane = t & 63;
  __shared__ float reds[4][8], redq[4][8];
#pragma unroll
  for (int r = 0; r < 8; r++) {
    float s = ssum[r], qq = sq[r];
#pragma unroll
    for (int off = 32; off > 0; off >>= 1) {
      s += __shfl_xor(s, off, 64);
      qq += __shfl_xor(qq, off, 64);
    }
    if (lane == 0) { reds[wave][r] = s; redq[wave][r] = qq; }
  }
  __syncthreads();

  float lw0 = lnw[c0], lw1 = lnw[c1], lb0 = lnb[c0], lb1 = lnb[c1];
#pragma unroll
  for (int r = 0; r < 8; r++) {
    float s = (reds[0][r] + reds[1][r]) + (reds[2][r] + reds[3][r]);
    float qq = (redq[0][r] + redq[1][r]) + (redq[2][r] + redq[3][r]);
    float mu = s * (1.f / 512.f);
    float var = qq * (1.f / 512.f) - mu * mu;
    float rstd = rsqrtf(var + 1e-5f);
    out[(size_t)(r0 + r) * DM + c0] = (y0[r] - mu) * rstd * lw0 + lb0;
    out[(size_t)(r0 + r) * DM + c1] = (y1[r] - mu) * rstd * lw1 + lb1;
  }
}

// ---------------------------------------------------------------------------
extern "C" void kernel_launch(void* const* d_in, const int* in_sizes, int n_in,
                              void* d_out, int out_size, void* d_ws,
                              size_t ws_size, hipStream_t stream) {
  const float* q_in = (const float*)d_in[0];
  const float* k_in = (const float*)d_in[1];
  const float* v_in = (const float*)d_in[2];
  const int* mask = (const int*)d_in[3];
  const float* Wq = (const float*)d_in[4];
  const float* bq = (const float*)d_in[5];
  const float* Wk = (const float*)d_in[6];
  const float* bk = (const float*)d_in[7];
  const float* Wv = (const float*)d_in[8];
  const float* bv = (const float*)d_in[9];
  const float* Wo = (const float*)d_in[10];
  const float* bo = (const float*)d_in[11];
  const float* lnw = (const float*)d_in[12];
  const float* lnb = (const float*)d_in[13];
  float* out = (float*)d_out;

  float* ws = (float*)d_ws;
  constexpr size_t QKV = (size_t)B * H * S * DK;  // 786432 floats each
  float* Qw = ws;
  float* Kw = ws + QKV;
  float* Vw = ws + 2 * QKV;
  float* Aw = ws + 3 * QKV;                        // [B*S, 48]
  unsigned long long* bits = (unsigned long long*)(ws + 4 * QKV);
  // bits occupies BS*16*8 = 2 MB = 524288 floats
  ushort* Wt = (ushort*)(ws + 4 * QKV + (size_t)BS * 16 * 2);

  maskbits_kernel<<<BS / 4, 256, 0, stream>>>(mask, bits);
  wprep_kernel<<<3, 256, 0, stream>>>(Wq, Wk, Wv, Wt);
  proj_kernel<<<dim3(BS / 64, 3), 256, 0, stream>>>(
      q_in, k_in, v_in, Wt, bq, bk, bv, Qw, Kw, Vw);
  attn_kernel<<<(B * H * S) / 64, 256, 0, stream>>>(Qw, Kw, Vw, bits, Aw);
  out_ln_kernel<<<BS / 8, 256, 0, stream>>>(Aw, Wo, bo, q_in, lnw, lnb, out);
}

// Round 3
// 346.661 us; speedup vs baseline: 1.7333x; 1.4045x over previous
//
#include <hip/hip_runtime.h>

// Problem constants
constexpr int B = 16;
constexpr int S = 1024;
constexpr int DM = 512;        // D_MODEL
constexpr int H = 6;           // HEADS
constexpr int DK = 8;          // D_K == D_V
constexpr int NJ = H * DK;     // 48 projection cols per matrix
constexpr int BS = B * S;      // 16384 rows

typedef __attribute__((ext_vector_type(8))) short bf16x8;
typedef __attribute__((ext_vector_type(4))) float floatx4;

// exp2-domain: p = exp(score) = exp2(score*log2e); QSCALE folds 1/sqrt(8)*log2e
#define LOG2E 1.4426950408889634f
#define QSCALE (0.35355339059327373f * LOG2E)
#define MASKVAL (1e-9f * LOG2E)

__device__ inline ushort f2bf(float f) {
  unsigned int u = __builtin_bit_cast(unsigned int, f);
  return (ushort)((u + 0x7FFFu + ((u >> 16) & 1u)) >> 16);
}

// ---------------------------------------------------------------------------
// K0: mask int32 [B,S,S] -> bitmask [B*S, 16] uint64  (bit set => fill 1e-9)
__global__ __launch_bounds__(256) void maskbits_kernel(
    const int* __restrict__ mask, unsigned long long* __restrict__ bits) {
  int wave = threadIdx.x >> 6, lane = threadIdx.x & 63;
  int row = blockIdx.x * 4 + wave;            // [0, B*S)
  const int* mrow = mask + (size_t)row * S;
  unsigned long long* brow = bits + (size_t)row * 16;
#pragma unroll
  for (int c = 0; c < 16; c++) {
    int v = mrow[c * 64 + lane];
    unsigned long long bal = __ballot(v != 0);
    if (lane == 0) brow[c] = bal;
  }
}

// ---------------------------------------------------------------------------
// K0b: W prep — convert Wq/Wk/Wv fp32 [512][48] -> bf16 transposed [3][48][512]
__global__ __launch_bounds__(256) void wprep_kernel(
    const float* __restrict__ Wq, const float* __restrict__ Wk,
    const float* __restrict__ Wv, ushort* __restrict__ Wt) {
  int m = blockIdx.x;
  const float* W = (m == 0) ? Wq : (m == 1) ? Wk : Wv;
  ushort* dst = Wt + (size_t)m * NJ * DM;
  for (int e = threadIdx.x; e < DM * NJ; e += 256) {
    int k = e / NJ, n = e - k * NJ;
    dst[n * DM + k] = f2bf(W[e]);
  }
}

// ---------------------------------------------------------------------------
// K1: projections via bf16 MFMA. grid (BS/64, 3), block 256 (4 waves).
// Outputs bf16, layout [B,H,S,8]; Q pre-scaled by QSCALE (incl. log2e).
__global__ __launch_bounds__(256) void proj_kernel(
    const float* __restrict__ q_in, const float* __restrict__ k_in,
    const float* __restrict__ v_in, const ushort* __restrict__ Wt,
    const float* __restrict__ bq, const float* __restrict__ bk,
    const float* __restrict__ bv,
    ushort* __restrict__ Qo, ushort* __restrict__ Ko, ushort* __restrict__ Vo) {
  int m = blockIdx.y;
  const float* x    = (m == 0) ? q_in : (m == 1) ? k_in : v_in;
  const float* bias = (m == 0) ? bq   : (m == 1) ? bk   : bv;
  ushort* out       = (m == 0) ? Qo   : (m == 1) ? Ko   : Vo;
  float oscale      = (m == 0) ? QSCALE : 1.0f;
  const ushort* Wg  = Wt + (size_t)m * NJ * DM;

  constexpr int LDK = 264;   // padded bf16 row stride
  __shared__ ushort Xs[64 * LDK];   // 33.8 KB
  __shared__ ushort Ws[NJ * LDK];   // 25.3 KB

  int t = threadIdx.x;
  int r0 = blockIdx.x * 64;
  int wave = t >> 6, lane = t & 63;
  int mrow = lane & 15, quad = lane >> 4;

  floatx4 acc0 = {0.f, 0.f, 0.f, 0.f};
  floatx4 acc1 = {0.f, 0.f, 0.f, 0.f};
  floatx4 acc2 = {0.f, 0.f, 0.f, 0.f};

#pragma unroll 1
  for (int p = 0; p < 2; p++) {
    int k0 = p * 256;
    __syncthreads();
#pragma unroll
    for (int i = 0; i < 16; i++) {
      int f = t + i * 256;
      int r = f >> 6;
      int c = (f & 63) * 4;
      float4 g = *(const float4*)&x[(size_t)(r0 + r) * DM + k0 + c];
      ushort4 hh = {f2bf(g.x), f2bf(g.y), f2bf(g.z), f2bf(g.w)};
      *(ushort4*)&Xs[r * LDK + c] = hh;
    }
#pragma unroll
    for (int i = 0; i < 12; i++) {
      int f = t + i * 256;
      int n = f >> 6;
      int c = (f & 63) * 4;
      *(ushort4*)&Ws[n * LDK + c] = *(const ushort4*)&Wg[(size_t)n * DM + k0 + c];
    }
    __syncthreads();
#pragma unroll
    for (int kc = 0; kc < 8; kc++) {
      int koff = kc * 32 + quad * 8;
      bf16x8 a  = *(const bf16x8*)&Xs[(wave * 16 + mrow) * LDK + koff];
      bf16x8 b0 = *(const bf16x8*)&Ws[(0  + mrow) * LDK + koff];
      bf16x8 b1 = *(const bf16x8*)&Ws[(16 + mrow) * LDK + koff];
      bf16x8 b2 = *(const bf16x8*)&Ws[(32 + mrow) * LDK + koff];
      acc0 = __builtin_amdgcn_mfma_f32_16x16x32_bf16(a, b0, acc0, 0, 0, 0);
      acc1 = __builtin_amdgcn_mfma_f32_16x16x32_bf16(a, b1, acc1, 0, 0, 0);
      acc2 = __builtin_amdgcn_mfma_f32_16x16x32_bf16(a, b2, acc2, 0, 0, 0);
    }
  }

  // epilogue: C/D layout col=lane&15, row=quad*4+reg
  int baseR = r0 + wave * 16 + quad * 4;
#pragma unroll
  for (int j = 0; j < 3; j++) {
    floatx4 a = (j == 0) ? acc0 : (j == 1) ? acc1 : acc2;
    int n = j * 16 + mrow;
    float bn = bias[n];
    int h = n >> 3, d = n & 7;
#pragma unroll
    for (int r = 0; r < 4; r++) {
      int R = baseR + r;
      int b = R >> 10, s = R & 1023;
      out[(((size_t)(b * H + h)) * S + s) * 8 + d] = f2bf((a[r] + bn) * oscale);
    }
  }
}

// ---------------------------------------------------------------------------
// K2: MFMA attention. grid 1536 (B*H*S/64), block 256 (4 waves).
// Block: one (b,h), 64 queries; all 1024 keys staged in LDS once.
// Wave w owns queries [w*16, w*16+16), loops 32 chunks of 32 keys:
//   scores (2x QK^T MFMA, d padded 8->32 by zero A-quads) -> mask+exp2 ->
//   bf16 pack -> wave-private LDS P tile -> PV MFMA (ones col = denominator).
// Key order inside a chunk is permuted (n, n+16 interleave) identically in P
// and Vt — reduction order irrelevant.
__global__ __launch_bounds__(256) void attn_kernel(
    const ushort* __restrict__ Qg, const ushort* __restrict__ Kg,
    const ushort* __restrict__ Vg, const unsigned long long* __restrict__ bits,
    float* __restrict__ A) {
  int bh = blockIdx.x >> 4;
  int qt = blockIdx.x & 15;
  int b = bh / H, h = bh % H;
  int q0 = qt * 64;

  __shared__ ushort Ks[1024 * 8];                 // 16 KB, [key][8]
  __shared__ ushort Vt[9 * 1032];                 // 18.1 KB, [d(+ones)][pos]
  __shared__ unsigned long long Mw[64 * 16];      // 8 KB
  __shared__ uint Pb[4][2][16 * 20];              // 10 KB: wave x parity x 16 rows x 80B

  int t = threadIdx.x;
  int wave = t >> 6, lane = t & 63;
  int quad = lane >> 4, n16 = lane & 15;

  const ushort* Kbase = Kg + (size_t)bh * S * 8;
  const ushort* Vbase = Vg + (size_t)bh * S * 8;
  const unsigned long long* Bbase = bits + ((size_t)(b * S + q0)) * 16;

  // ---- stage K (linear 16 KB) ----
#pragma unroll
  for (int i = 0; i < 4; i++) {
    int e = t + i * 256;        // uint4 index among 1024
    *(uint4*)&Ks[e * 8] = *(const uint4*)&Kbase[e * 8];
  }
  // ---- stage Vt (transposed + key-permuted) ----
#pragma unroll
  for (int i = 0; i < 8; i++) {
    int e = t + i * 256;        // ushort4 index among 2048
    int key = e >> 1, db = (e & 1) << 2;
    ushort4 v = *(const ushort4*)&Vbase[key * 8 + db];
    int g = (key & ~31) + 2 * (key & 15) + ((key >> 4) & 1);
    Vt[(db + 0) * 1032 + g] = v.x;
    Vt[(db + 1) * 1032 + g] = v.y;
    Vt[(db + 2) * 1032 + g] = v.z;
    Vt[(db + 3) * 1032 + g] = v.w;
  }
  // ones row (bf16 1.0) for the denominator column
#pragma unroll
  for (int i = 0; i < 4; i++) Vt[8 * 1032 + t + i * 256] = 0x3F80;
  // ---- stage mask words (linear 8 KB) ----
#pragma unroll
  for (int i = 0; i < 4; i++) Mw[t + i * 256] = Bbase[t + i * 256];
  __syncthreads();

  // Q A-frag: quad 0 holds d=0..7, other quads zero (kills padded K-range)
  bf16x8 aq = {0, 0, 0, 0, 0, 0, 0, 0};
  if (quad == 0)
    aq = *(const bf16x8*)&Qg[((size_t)bh * S + q0 + wave * 16 + n16) * 8];

  floatx4 acc = {0.f, 0.f, 0.f, 0.f};
  const floatx4 zero = {0.f, 0.f, 0.f, 0.f};

#pragma unroll 2
  for (int c = 0; c < 32; c++) {
    // scores for 16q x 32keys (two 16-key tiles)
    bf16x8 bk0 = *(const bf16x8*)&Ks[(c * 32 + n16) * 8];
    bf16x8 bk1 = *(const bf16x8*)&Ks[(c * 32 + 16 + n16) * 8];
    floatx4 sc0 = __builtin_amdgcn_mfma_f32_16x16x32_bf16(aq, bk0, zero, 0, 0, 0);
    floatx4 sc1 = __builtin_amdgcn_mfma_f32_16x16x32_bf16(aq, bk1, zero, 0, 0, 0);

    int basebit = (c & 1) * 32;
    int wi = c >> 1;
    uint* prow = &Pb[wave][c & 1][0];
#pragma unroll
    for (int r = 0; r < 4; r++) {
      unsigned long long mw = Mw[(wave * 16 + quad * 4 + r) * 16 + wi];
      float s0 = ((mw >> (basebit + n16)) & 1ull) ? MASKVAL : sc0[r];
      float s1 = ((mw >> (basebit + 16 + n16)) & 1ull) ? MASKVAL : sc1[r];
      float p0 = exp2f(fminf(s0, 80.f));
      float p1 = exp2f(fminf(s1, 80.f));
      uint pw = (uint)f2bf(p0) | ((uint)f2bf(p1) << 16);
      prow[(quad * 4 + r) * 20 + n16] = pw;   // dword n16 = keys (n16, n16+16)
    }

    // P A-frag: row n16, 16B at quad*16
    bf16x8 ap = *(const bf16x8*)((const ushort*)prow + n16 * 40 + quad * 8);
    // Vt B-frag: lane col = d (0..7 data, 8 = ones; 9..15 read row 8, ignored)
    int dd = (n16 < 9) ? n16 : 8;
    bf16x8 bv = *(const bf16x8*)&Vt[dd * 1032 + c * 32 + quad * 8];
    acc = __builtin_amdgcn_mfma_f32_16x16x32_bf16(ap, bv, acc, 0, 0, 0);
  }

  // normalize: denominator sits in col 8 of each row
#pragma unroll
  for (int r = 0; r < 4; r++) {
    float dnm = __shfl(acc[r], (lane & 48) | 8, 64);
    if (n16 < 8) {
      int qg = q0 + wave * 16 + quad * 4 + r;
      A[((size_t)(b * S + qg)) * NJ + h * 8 + n16] = acc[r] / dnm;
    }
  }
}

// ---------------------------------------------------------------------------
// K3: out = A@Wo + bo + residual, then LayerNorm. grid BS/8, block 256.
__global__ __launch_bounds__(256) void out_ln_kernel(
    const float* __restrict__ A, const float* __restrict__ Wo,
    const float* __restrict__ bo, const float* __restrict__ qin,
    const float* __restrict__ lnw, const float* __restrict__ lnb,
    float* __restrict__ out) {
  int r0 = blockIdx.x * 8;
  int t = threadIdx.x;
  __shared__ float As[8 * NJ];
#pragma unroll
  for (int i = t; i < 8 * NJ; i += 256) As[i] = A[(size_t)r0 * NJ + i];
  __syncthreads();

  int c0 = t, c1 = t + 256;
  float acc0[8], acc1[8];
#pragma unroll
  for (int r = 0; r < 8; r++) { acc0[r] = 0.f; acc1[r] = 0.f; }

#pragma unroll 4
  for (int j = 0; j < NJ; j++) {
    float w0 = Wo[(size_t)j * DM + c0];
    float w1 = Wo[(size_t)j * DM + c1];
#pragma unroll
    for (int r = 0; r < 8; r++) {
      float a = As[r * NJ + j];
      acc0[r] += a * w0;
      acc1[r] += a * w1;
    }
  }

  float b0 = bo[c0], b1 = bo[c1];
  float y0[8], y1[8], ssum[8], sq[8];
#pragma unroll
  for (int r = 0; r < 8; r++) {
    y0[r] = acc0[r] + b0 + qin[(size_t)(r0 + r) * DM + c0];
    y1[r] = acc1[r] + b1 + qin[(size_t)(r0 + r) * DM + c1];
    ssum[r] = y0[r] + y1[r];
    sq[r] = y0[r] * y0[r] + y1[r] * y1[r];
  }

  int wave = t >> 6, lane = t & 63;
  __shared__ float reds[4][8], redq[4][8];
#pragma unroll
  for (int r = 0; r < 8; r++) {
    float s = ssum[r], qq = sq[r];
#pragma unroll
    for (int off = 32; off > 0; off >>= 1) {
      s += __shfl_xor(s, off, 64);
      qq += __shfl_xor(qq, off, 64);
    }
    if (lane == 0) { reds[wave][r] = s; redq[wave][r] = qq; }
  }
  __syncthreads();

  float lw0 = lnw[c0], lw1 = lnw[c1], lb0 = lnb[c0], lb1 = lnb[c1];
#pragma unroll
  for (int r = 0; r < 8; r++) {
    float s = (reds[0][r] + reds[1][r]) + (reds[2][r] + reds[3][r]);
    float qq = (redq[0][r] + redq[1][r]) + (redq[2][r] + redq[3][r]);
    float mu = s * (1.f / 512.f);
    float var = qq * (1.f / 512.f) - mu * mu;
    float rstd = rsqrtf(var + 1e-5f);
    out[(size_t)(r0 + r) * DM + c0] = (y0[r] - mu) * rstd * lw0 + lb0;
    out[(size_t)(r0 + r) * DM + c1] = (y1[r] - mu) * rstd * lw1 + lb1;
  }
}

// ---------------------------------------------------------------------------
extern "C" void kernel_launch(void* const* d_in, const int* in_sizes, int n_in,
                              void* d_out, int out_size, void* d_ws,
                              size_t ws_size, hipStream_t stream) {
  const float* q_in = (const float*)d_in[0];
  const float* k_in = (const float*)d_in[1];
  const float* v_in = (const float*)d_in[2];
  const int* mask = (const int*)d_in[3];
  const float* Wq = (const float*)d_in[4];
  const float* bq = (const float*)d_in[5];
  const float* Wk = (const float*)d_in[6];
  const float* bk = (const float*)d_in[7];
  const float* Wv = (const float*)d_in[8];
  const float* bv = (const float*)d_in[9];
  const float* Wo = (const float*)d_in[10];
  const float* bo = (const float*)d_in[11];
  const float* lnw = (const float*)d_in[12];
  const float* lnb = (const float*)d_in[13];
  float* out = (float*)d_out;

  constexpr size_t QKV = (size_t)B * H * S * DK;  // 786432 elements each
  ushort* base = (ushort*)d_ws;
  ushort* Qw = base;
  ushort* Kw = base + QKV;
  ushort* Vw = base + 2 * QKV;            // 3*QKV ushorts = 4.5 MB
  float* Aw = (float*)(base + 3 * QKV);   // BS*48 floats = 3 MB
  unsigned long long* bits = (unsigned long long*)(Aw + (size_t)BS * NJ);  // 2 MB
  ushort* Wt = (ushort*)(bits + (size_t)BS * 16);  // 3*48*512 bf16

  maskbits_kernel<<<BS / 4, 256, 0, stream>>>(mask, bits);
  wprep_kernel<<<3, 256, 0, stream>>>(Wq, Wk, Wv, Wt);
  proj_kernel<<<dim3(BS / 64, 3), 256, 0, stream>>>(
      q_in, k_in, v_in, Wt, bq, bk, bv, Qw, Kw, Vw);
  attn_kernel<<<(B * H * S) / 64, 256, 0, stream>>>(Qw, Kw, Vw, bits, Aw);
  out_ln_kernel<<<BS / 8, 256, 0, stream>>>(Aw, Wo, bo, q_in, lnw, lnb, out);
}

// Round 4
// 316.644 us; speedup vs baseline: 1.8976x; 1.0948x over previous
//
#include <hip/hip_runtime.h>

// Problem constants
constexpr int B = 16;
constexpr int S = 1024;
constexpr int DM = 512;        // D_MODEL
constexpr int H = 6;           // HEADS
constexpr int DK = 8;          // D_K == D_V
constexpr int NJ = H * DK;     // 48 projection cols per matrix
constexpr int BS = B * S;      // 16384 rows
constexpr int WB_ELEMS = 16 * NJ * 32;  // 24576 ushorts per matrix (B-frag order)

typedef __attribute__((ext_vector_type(8))) short bf16x8;
typedef __attribute__((ext_vector_type(4))) float floatx4;

// exp2-domain: p = exp(score) = exp2(score*log2e); QSCALE folds 1/sqrt(8)*log2e
#define LOG2E 1.4426950408889634f
#define QSCALE (0.35355339059327373f * LOG2E)
#define MASKVAL (1e-9f * LOG2E)

__device__ inline ushort f2bf(float f) {
  unsigned int u = __builtin_bit_cast(unsigned int, f);
  return (ushort)((u + 0x7FFFu + ((u >> 16) & 1u)) >> 16);
}

// ---------------------------------------------------------------------------
// K0: mask int32 [B,S,S] -> bitmask [B*S, 16] uint64  (bit set => fill 1e-9)
__global__ __launch_bounds__(256) void maskbits_kernel(
    const int* __restrict__ mask, unsigned long long* __restrict__ bits) {
  int wave = threadIdx.x >> 6, lane = threadIdx.x & 63;
  int row = blockIdx.x * 4 + wave;            // [0, B*S)
  const int* mrow = mask + (size_t)row * S;
  unsigned long long* brow = bits + (size_t)row * 16;
#pragma unroll
  for (int c = 0; c < 16; c++) {
    int v = mrow[c * 64 + lane];
    unsigned long long bal = __ballot(v != 0);
    if (lane == 0) brow[c] = bal;
  }
}

// ---------------------------------------------------------------------------
// K0b: W prep — fp32 [512][48] -> bf16 B-frag-ordered tiles:
// Wb[m][(kc*48 + n)*32 + kj] = bf16(W[kc*32+kj][n]);  kc=0..15, kj=0..31
__global__ __launch_bounds__(256) void wprep_kernel(
    const float* __restrict__ Wq, const float* __restrict__ Wk,
    const float* __restrict__ Wv, ushort* __restrict__ Wb) {
  int m = blockIdx.x;
  const float* W = (m == 0) ? Wq : (m == 1) ? Wk : Wv;
  ushort* dst = Wb + (size_t)m * WB_ELEMS;
  for (int e = threadIdx.x; e < WB_ELEMS; e += 256) {
    int kc = e >> 11;              // /(48*32)... careful: 48*32=1536 not pow2
    kc = e / 1536;
    int rem = e - kc * 1536;
    int n = rem >> 5, kj = rem & 31;
    dst[e] = f2bf(W[(size_t)(kc * 32 + kj) * NJ + n]);
  }
}

// ---------------------------------------------------------------------------
// K1: projections via bf16 MFMA. grid (BS/64, 3), block 256 (4 waves).
// W staged once in LDS (B-frag order, contiguous reads, conflict-free);
// X A-frags loaded straight from global into regs (no barriers in K-loop).
// Outputs bf16, layout [B,H,S,8]; Q pre-scaled by QSCALE (incl. log2e).
__global__ __launch_bounds__(256) void proj_kernel(
    const float* __restrict__ q_in, const float* __restrict__ k_in,
    const float* __restrict__ v_in, const ushort* __restrict__ Wb,
    const float* __restrict__ bq, const float* __restrict__ bk,
    const float* __restrict__ bv,
    ushort* __restrict__ Qo, ushort* __restrict__ Ko, ushort* __restrict__ Vo) {
  int m = blockIdx.y;
  const float* x    = (m == 0) ? q_in : (m == 1) ? k_in : v_in;
  const float* bias = (m == 0) ? bq   : (m == 1) ? bk   : bv;
  ushort* out       = (m == 0) ? Qo   : (m == 1) ? Ko   : Vo;
  float oscale      = (m == 0) ? QSCALE : 1.0f;
  const ushort* Wg  = Wb + (size_t)m * WB_ELEMS;

  __shared__ ushort Wl[WB_ELEMS];   // 48 KB -> 3 blocks/CU

  int t = threadIdx.x;
  // stage W once: contiguous uint4 copies (coalesced, conflict-free)
  {
    const uint4* src = (const uint4*)Wg;
    uint4* dst = (uint4*)Wl;
#pragma unroll
    for (int i = 0; i < 12; i++) dst[t + i * 256] = src[t + i * 256];
  }

  int r0 = blockIdx.x * 64;
  int wave = t >> 6, lane = t & 63;
  int n16 = lane & 15, quad = lane >> 4;
  const float* xrow = x + (size_t)(r0 + wave * 16 + n16) * DM + quad * 8;

  floatx4 acc0 = {0.f, 0.f, 0.f, 0.f};
  floatx4 acc1 = {0.f, 0.f, 0.f, 0.f};
  floatx4 acc2 = {0.f, 0.f, 0.f, 0.f};

  __syncthreads();

#pragma unroll 4
  for (int kc = 0; kc < 16; kc++) {
    float4 xa = *(const float4*)(xrow + kc * 32);
    float4 xb = *(const float4*)(xrow + kc * 32 + 4);
    bf16x8 a;
    a[0] = (short)f2bf(xa.x); a[1] = (short)f2bf(xa.y);
    a[2] = (short)f2bf(xa.z); a[3] = (short)f2bf(xa.w);
    a[4] = (short)f2bf(xb.x); a[5] = (short)f2bf(xb.y);
    a[6] = (short)f2bf(xb.z); a[7] = (short)f2bf(xb.w);
    const ushort* wbase = &Wl[(kc * 48 + n16) * 32 + quad * 8];
    bf16x8 b0 = *(const bf16x8*)(wbase);
    bf16x8 b1 = *(const bf16x8*)(wbase + 16 * 32);
    bf16x8 b2 = *(const bf16x8*)(wbase + 32 * 32);
    acc0 = __builtin_amdgcn_mfma_f32_16x16x32_bf16(a, b0, acc0, 0, 0, 0);
    acc1 = __builtin_amdgcn_mfma_f32_16x16x32_bf16(a, b1, acc1, 0, 0, 0);
    acc2 = __builtin_amdgcn_mfma_f32_16x16x32_bf16(a, b2, acc2, 0, 0, 0);
  }

  // epilogue: C/D layout col=lane&15, row=quad*4+reg
  int baseR = r0 + wave * 16 + quad * 4;
#pragma unroll
  for (int j = 0; j < 3; j++) {
    floatx4 a = (j == 0) ? acc0 : (j == 1) ? acc1 : acc2;
    int n = j * 16 + n16;
    float bn = bias[n];
    int h = n >> 3, d = n & 7;
#pragma unroll
    for (int r = 0; r < 4; r++) {
      int R = baseR + r;
      int b = R >> 10, s = R & 1023;
      out[(((size_t)(b * H + h)) * S + s) * 8 + d] = f2bf((a[r] + bn) * oscale);
    }
  }
}

// ---------------------------------------------------------------------------
// K2: MFMA attention. grid 1536 (B*H*S/64), block 256 (4 waves).
__global__ __launch_bounds__(256) void attn_kernel(
    const ushort* __restrict__ Qg, const ushort* __restrict__ Kg,
    const ushort* __restrict__ Vg, const unsigned long long* __restrict__ bits,
    float* __restrict__ A) {
  int bh = blockIdx.x >> 4;
  int qt = blockIdx.x & 15;
  int b = bh / H, h = bh % H;
  int q0 = qt * 64;

  __shared__ ushort Ks[1024 * 8];                 // 16 KB, [key][8]
  __shared__ ushort Vt[9 * 1032];                 // 18.1 KB, [d(+ones)][pos]
  __shared__ unsigned long long Mw[64 * 16];      // 8 KB
  __shared__ uint Pb[4][2][16 * 20];              // 10 KB

  int t = threadIdx.x;
  int wave = t >> 6, lane = t & 63;
  int quad = lane >> 4, n16 = lane & 15;

  const ushort* Kbase = Kg + (size_t)bh * S * 8;
  const ushort* Vbase = Vg + (size_t)bh * S * 8;
  const unsigned long long* Bbase = bits + ((size_t)(b * S + q0)) * 16;

#pragma unroll
  for (int i = 0; i < 4; i++) {
    int e = t + i * 256;
    *(uint4*)&Ks[e * 8] = *(const uint4*)&Kbase[e * 8];
  }
#pragma unroll
  for (int i = 0; i < 8; i++) {
    int e = t + i * 256;
    int key = e >> 1, db = (e & 1) << 2;
    ushort4 v = *(const ushort4*)&Vbase[key * 8 + db];
    int g = (key & ~31) + 2 * (key & 15) + ((key >> 4) & 1);
    Vt[(db + 0) * 1032 + g] = v.x;
    Vt[(db + 1) * 1032 + g] = v.y;
    Vt[(db + 2) * 1032 + g] = v.z;
    Vt[(db + 3) * 1032 + g] = v.w;
  }
#pragma unroll
  for (int i = 0; i < 4; i++) Vt[8 * 1032 + t + i * 256] = 0x3F80;
#pragma unroll
  for (int i = 0; i < 4; i++) Mw[t + i * 256] = Bbase[t + i * 256];
  __syncthreads();

  bf16x8 aq = {0, 0, 0, 0, 0, 0, 0, 0};
  if (quad == 0)
    aq = *(const bf16x8*)&Qg[((size_t)bh * S + q0 + wave * 16 + n16) * 8];

  floatx4 acc = {0.f, 0.f, 0.f, 0.f};
  const floatx4 zero = {0.f, 0.f, 0.f, 0.f};

#pragma unroll 2
  for (int c = 0; c < 32; c++) {
    bf16x8 bk0 = *(const bf16x8*)&Ks[(c * 32 + n16) * 8];
    bf16x8 bk1 = *(const bf16x8*)&Ks[(c * 32 + 16 + n16) * 8];
    floatx4 sc0 = __builtin_amdgcn_mfma_f32_16x16x32_bf16(aq, bk0, zero, 0, 0, 0);
    floatx4 sc1 = __builtin_amdgcn_mfma_f32_16x16x32_bf16(aq, bk1, zero, 0, 0, 0);

    int basebit = (c & 1) * 32;
    int wi = c >> 1;
    uint* prow = &Pb[wave][c & 1][0];
#pragma unroll
    for (int r = 0; r < 4; r++) {
      unsigned long long mw = Mw[(wave * 16 + quad * 4 + r) * 16 + wi];
      float s0 = ((mw >> (basebit + n16)) & 1ull) ? MASKVAL : sc0[r];
      float s1 = ((mw >> (basebit + 16 + n16)) & 1ull) ? MASKVAL : sc1[r];
      float p0 = exp2f(fminf(s0, 80.f));
      float p1 = exp2f(fminf(s1, 80.f));
      uint pw = (uint)f2bf(p0) | ((uint)f2bf(p1) << 16);
      prow[(quad * 4 + r) * 20 + n16] = pw;
    }

    bf16x8 ap = *(const bf16x8*)((const ushort*)prow + n16 * 40 + quad * 8);
    int dd = (n16 < 9) ? n16 : 8;
    bf16x8 bv = *(const bf16x8*)&Vt[dd * 1032 + c * 32 + quad * 8];
    acc = __builtin_amdgcn_mfma_f32_16x16x32_bf16(ap, bv, acc, 0, 0, 0);
  }

#pragma unroll
  for (int r = 0; r < 4; r++) {
    float dnm = __shfl(acc[r], (lane & 48) | 8, 64);
    if (n16 < 8) {
      int qg = q0 + wave * 16 + quad * 4 + r;
      A[((size_t)(b * S + qg)) * NJ + h * 8 + n16] = acc[r] / dnm;
    }
  }
}

// ---------------------------------------------------------------------------
// K3: out = A@Wo + bo + residual, then LayerNorm. grid BS/8, block 256.
__global__ __launch_bounds__(256) void out_ln_kernel(
    const float* __restrict__ A, const float* __restrict__ Wo,
    const float* __restrict__ bo, const float* __restrict__ qin,
    const float* __restrict__ lnw, const float* __restrict__ lnb,
    float* __restrict__ out) {
  int r0 = blockIdx.x * 8;
  int t = threadIdx.x;
  __shared__ float As[8 * NJ];
#pragma unroll
  for (int i = t; i < 8 * NJ; i += 256) As[i] = A[(size_t)r0 * NJ + i];
  __syncthreads();

  int c0 = t, c1 = t + 256;
  float acc0[8], acc1[8];
#pragma unroll
  for (int r = 0; r < 8; r++) { acc0[r] = 0.f; acc1[r] = 0.f; }

#pragma unroll 4
  for (int j = 0; j < NJ; j++) {
    float w0 = Wo[(size_t)j * DM + c0];
    float w1 = Wo[(size_t)j * DM + c1];
#pragma unroll
    for (int r = 0; r < 8; r++) {
      float a = As[r * NJ + j];
      acc0[r] += a * w0;
      acc1[r] += a * w1;
    }
  }

  float b0 = bo[c0], b1 = bo[c1];
  float y0[8], y1[8], ssum[8], sq[8];
#pragma unroll
  for (int r = 0; r < 8; r++) {
    y0[r] = acc0[r] + b0 + qin[(size_t)(r0 + r) * DM + c0];
    y1[r] = acc1[r] + b1 + qin[(size_t)(r0 + r) * DM + c1];
    ssum[r] = y0[r] + y1[r];
    sq[r] = y0[r] * y0[r] + y1[r] * y1[r];
  }

  int wave = t >> 6, lane = t & 63;
  __shared__ float reds[4][8], redq[4][8];
#pragma unroll
  for (int r = 0; r < 8; r++) {
    float s = ssum[r], qq = sq[r];
#pragma unroll
    for (int off = 32; off > 0; off >>= 1) {
      s += __shfl_xor(s, off, 64);
      qq += __shfl_xor(qq, off, 64);
    }
    if (lane == 0) { reds[wave][r] = s; redq[wave][r] = qq; }
  }
  __syncthreads();

  float lw0 = lnw[c0], lw1 = lnw[c1], lb0 = lnb[c0], lb1 = lnb[c1];
#pragma unroll
  for (int r = 0; r < 8; r++) {
    float s = (reds[0][r] + reds[1][r]) + (reds[2][r] + reds[3][r]);
    float qq = (redq[0][r] + redq[1][r]) + (redq[2][r] + redq[3][r]);
    float mu = s * (1.f / 512.f);
    float var = qq * (1.f / 512.f) - mu * mu;
    float rstd = rsqrtf(var + 1e-5f);
    out[(size_t)(r0 + r) * DM + c0] = (y0[r] - mu) * rstd * lw0 + lb0;
    out[(size_t)(r0 + r) * DM + c1] = (y1[r] - mu) * rstd * lw1 + lb1;
  }
}

// ---------------------------------------------------------------------------
extern "C" void kernel_launch(void* const* d_in, const int* in_sizes, int n_in,
                              void* d_out, int out_size, void* d_ws,
                              size_t ws_size, hipStream_t stream) {
  const float* q_in = (const float*)d_in[0];
  const float* k_in = (const float*)d_in[1];
  const float* v_in = (const float*)d_in[2];
  const int* mask = (const int*)d_in[3];
  const float* Wq = (const float*)d_in[4];
  const float* bq = (const float*)d_in[5];
  const float* Wk = (const float*)d_in[6];
  const float* bk = (const float*)d_in[7];
  const float* Wv = (const float*)d_in[8];
  const float* bv = (const float*)d_in[9];
  const float* Wo = (const float*)d_in[10];
  const float* bo = (const float*)d_in[11];
  const float* lnw = (const float*)d_in[12];
  const float* lnb = (const float*)d_in[13];
  float* out = (float*)d_out;

  constexpr size_t QKV = (size_t)B * H * S * DK;  // 786432 elements each
  ushort* base = (ushort*)d_ws;
  ushort* Qw = base;
  ushort* Kw = base + QKV;
  ushort* Vw = base + 2 * QKV;            // 3*QKV ushorts = 4.5 MB
  float* Aw = (float*)(base + 3 * QKV);   // BS*48 floats = 3 MB
  unsigned long long* bits = (unsigned long long*)(Aw + (size_t)BS * NJ);  // 2 MB
  ushort* Wb = (ushort*)(bits + (size_t)BS * 16);  // 3*24576 bf16

  maskbits_kernel<<<BS / 4, 256, 0, stream>>>(mask, bits);
  wprep_kernel<<<3, 256, 0, stream>>>(Wq, Wk, Wv, Wb);
  proj_kernel<<<dim3(BS / 64, 3), 256, 0, stream>>>(
      q_in, k_in, v_in, Wb, bq, bk, bv, Qw, Kw, Vw);
  attn_kernel<<<(B * H * S) / 64, 256, 0, stream>>>(Qw, Kw, Vw, bits, Aw);
  out_ln_kernel<<<BS / 8, 256, 0, stream>>>(Aw, Wo, bo, q_in, lnw, lnb, out);
}

// Round 5
// 310.426 us; speedup vs baseline: 1.9356x; 1.0200x over previous
//
#include <hip/hip_runtime.h>

// Problem constants
constexpr int B = 16;
constexpr int S = 1024;
constexpr int DM = 512;        // D_MODEL
constexpr int H = 6;           // HEADS
constexpr int DK = 8;          // D_K == D_V
constexpr int NJ = H * DK;     // 48 projection cols per matrix
constexpr int BS = B * S;      // 16384 rows
constexpr int WB_ELEMS = 16 * NJ * 32;  // 24576 ushorts per matrix (B-frag order)

typedef __attribute__((ext_vector_type(8))) short bf16x8;
typedef __attribute__((ext_vector_type(8))) _Float16 half8;
typedef __attribute__((ext_vector_type(4))) float floatx4;

// exp2-domain: p = exp(score) = exp2(score*log2e); QSCALE folds 1/sqrt(8)*log2e
#define LOG2E 1.4426950408889634f
#define QSCALE (0.35355339059327373f * LOG2E)

__device__ inline ushort f2bf(float f) {
  unsigned int u = __builtin_bit_cast(unsigned int, f);
  return (ushort)((u + 0x7FFFu + ((u >> 16) & 1u)) >> 16);
}

// ---------------------------------------------------------------------------
// K0: mask int32 [B,S,S] -> bitmask [B*S, 32] uint32 (bit set => fill 1e-9)
__global__ __launch_bounds__(256) void maskbits_kernel(
    const int* __restrict__ mask, unsigned long long* __restrict__ bits) {
  int wave = threadIdx.x >> 6, lane = threadIdx.x & 63;
  int row = blockIdx.x * 4 + wave;            // [0, B*S)
  const int* mrow = mask + (size_t)row * S;
  unsigned long long* brow = bits + (size_t)row * 16;
#pragma unroll
  for (int c = 0; c < 16; c++) {
    int v = mrow[c * 64 + lane];
    unsigned long long bal = __ballot(v != 0);
    if (lane == 0) brow[c] = bal;
  }
}

// ---------------------------------------------------------------------------
// K0b: W prep — fp32 [512][48] -> bf16 B-frag-ordered tiles:
// Wb[m][(kc*48 + n)*32 + kj] = bf16(W[kc*32+kj][n]);  kc=0..15, kj=0..31
__global__ __launch_bounds__(256) void wprep_kernel(
    const float* __restrict__ Wq, const float* __restrict__ Wk,
    const float* __restrict__ Wv, ushort* __restrict__ Wb) {
  int m = blockIdx.x;
  const float* W = (m == 0) ? Wq : (m == 1) ? Wk : Wv;
  ushort* dst = Wb + (size_t)m * WB_ELEMS;
  for (int e = threadIdx.x; e < WB_ELEMS; e += 256) {
    int kc = e / 1536;
    int rem = e - kc * 1536;
    int n = rem >> 5, kj = rem & 31;
    dst[e] = f2bf(W[(size_t)(kc * 32 + kj) * NJ + n]);
  }
}

// ---------------------------------------------------------------------------
// K1: projections via bf16 MFMA. grid (BS/64, 3), block 256 (4 waves).
// W staged once in LDS (B-frag order); X A-frags straight from global.
// Q/K out bf16 (Q pre-scaled by QSCALE incl. log2e); V out fp16.
__global__ __launch_bounds__(256) void proj_kernel(
    const float* __restrict__ q_in, const float* __restrict__ k_in,
    const float* __restrict__ v_in, const ushort* __restrict__ Wb,
    const float* __restrict__ bq, const float* __restrict__ bk,
    const float* __restrict__ bv,
    ushort* __restrict__ Qo, ushort* __restrict__ Ko, ushort* __restrict__ Vo) {
  int m = blockIdx.y;
  const float* x    = (m == 0) ? q_in : (m == 1) ? k_in : v_in;
  const float* bias = (m == 0) ? bq   : (m == 1) ? bk   : bv;
  ushort* out       = (m == 0) ? Qo   : (m == 1) ? Ko   : Vo;
  float oscale      = (m == 0) ? QSCALE : 1.0f;
  const ushort* Wg  = Wb + (size_t)m * WB_ELEMS;

  __shared__ ushort Wl[WB_ELEMS];   // 48 KB -> 3 blocks/CU

  int t = threadIdx.x;
  {
    const uint4* src = (const uint4*)Wg;
    uint4* dst = (uint4*)Wl;
#pragma unroll
    for (int i = 0; i < 12; i++) dst[t + i * 256] = src[t + i * 256];
  }

  int r0 = blockIdx.x * 64;
  int wave = t >> 6, lane = t & 63;
  int n16 = lane & 15, quad = lane >> 4;
  const float* xrow = x + (size_t)(r0 + wave * 16 + n16) * DM + quad * 8;

  floatx4 acc0 = {0.f, 0.f, 0.f, 0.f};
  floatx4 acc1 = {0.f, 0.f, 0.f, 0.f};
  floatx4 acc2 = {0.f, 0.f, 0.f, 0.f};

  __syncthreads();

#pragma unroll 4
  for (int kc = 0; kc < 16; kc++) {
    float4 xa = *(const float4*)(xrow + kc * 32);
    float4 xb = *(const float4*)(xrow + kc * 32 + 4);
    bf16x8 a;
    a[0] = (short)f2bf(xa.x); a[1] = (short)f2bf(xa.y);
    a[2] = (short)f2bf(xa.z); a[3] = (short)f2bf(xa.w);
    a[4] = (short)f2bf(xb.x); a[5] = (short)f2bf(xb.y);
    a[6] = (short)f2bf(xb.z); a[7] = (short)f2bf(xb.w);
    const ushort* wbase = &Wl[(kc * 48 + n16) * 32 + quad * 8];
    bf16x8 b0 = *(const bf16x8*)(wbase);
    bf16x8 b1 = *(const bf16x8*)(wbase + 16 * 32);
    bf16x8 b2 = *(const bf16x8*)(wbase + 32 * 32);
    acc0 = __builtin_amdgcn_mfma_f32_16x16x32_bf16(a, b0, acc0, 0, 0, 0);
    acc1 = __builtin_amdgcn_mfma_f32_16x16x32_bf16(a, b1, acc1, 0, 0, 0);
    acc2 = __builtin_amdgcn_mfma_f32_16x16x32_bf16(a, b2, acc2, 0, 0, 0);
  }

  // epilogue: C/D layout col=lane&15, row=quad*4+reg
  int baseR = r0 + wave * 16 + quad * 4;
#pragma unroll
  for (int j = 0; j < 3; j++) {
    floatx4 a = (j == 0) ? acc0 : (j == 1) ? acc1 : acc2;
    int n = j * 16 + n16;
    float bn = bias[n];
    int h = n >> 3, d = n & 7;
#pragma unroll
    for (int r = 0; r < 4; r++) {
      int R = baseR + r;
      int b = R >> 10, s = R & 1023;
      float fv = (a[r] + bn) * oscale;
      ushort val = (m == 2) ? __builtin_bit_cast(ushort, (_Float16)fv)
                            : f2bf(fv);
      out[(((size_t)(b * H + h)) * S + s) * 8 + d] = val;
    }
  }
}

// ---------------------------------------------------------------------------
// K2: MFMA attention. grid 1536 (B*H*S/64), block 256 (4 waves).
// QK^T in bf16; P in fp16 (cvt_pkrtz), masked-fill via bit trick (fp16 1.0);
// PV in fp16 MFMA with ones-column denominator.
__global__ __launch_bounds__(256) void attn_kernel(
    const ushort* __restrict__ Qg, const ushort* __restrict__ Kg,
    const ushort* __restrict__ Vg /* fp16 */,
    const uint* __restrict__ bits32, float* __restrict__ A) {
  int bh = blockIdx.x >> 4;
  int qt = blockIdx.x & 15;
  int b = bh / H, h = bh % H;
  int q0 = qt * 64;

  __shared__ ushort Ks[1024 * 8];        // 16 KB, bf16 [key][8]
  __shared__ ushort Vt[9 * 1032];        // 18.1 KB, fp16 [d(+ones)][pos]
  __shared__ uint Mw[64 * 36];           // 9 KB, mask u32 words (padded)
  __shared__ uint Pb[4][16 * 20];        // 5 KB, per-wave fp16 P tile

  int t = threadIdx.x;
  int wave = t >> 6, lane = t & 63;
  int quad = lane >> 4, n16 = lane & 15;

  const ushort* Kbase = Kg + (size_t)bh * S * 8;
  const ushort* Vbase = Vg + (size_t)bh * S * 8;
  const uint* Bbase = bits32 + ((size_t)(b * S + q0)) * 32;

#pragma unroll
  for (int i = 0; i < 4; i++) {
    int e = t + i * 256;
    *(uint4*)&Ks[e * 8] = *(const uint4*)&Kbase[e * 8];
  }
#pragma unroll
  for (int i = 0; i < 8; i++) {
    int e = t + i * 256;
    int key = e >> 1, db = (e & 1) << 2;
    ushort4 v = *(const ushort4*)&Vbase[key * 8 + db];
    int g = (key & ~31) + 2 * (key & 15) + ((key >> 4) & 1);
    Vt[(db + 0) * 1032 + g] = v.x;
    Vt[(db + 1) * 1032 + g] = v.y;
    Vt[(db + 2) * 1032 + g] = v.z;
    Vt[(db + 3) * 1032 + g] = v.w;
  }
#pragma unroll
  for (int i = 0; i < 4; i++) Vt[8 * 1032 + t + i * 256] = 0x3C00;  // fp16 1.0
#pragma unroll
  for (int i = 0; i < 8; i++) {
    int e = t + i * 256;           // 2048 u32 words
    int row = e >> 5, w = e & 31;
    Mw[row * 36 + w] = Bbase[row * 32 + w];
  }
  __syncthreads();

  bf16x8 aq = {0, 0, 0, 0, 0, 0, 0, 0};
  if (quad == 0)
    aq = *(const bf16x8*)&Qg[((size_t)bh * S + q0 + wave * 16 + n16) * 8];

  floatx4 acc = {0.f, 0.f, 0.f, 0.f};
  const floatx4 zero = {0.f, 0.f, 0.f, 0.f};
  int row0 = wave * 16 + quad * 4;
  uint* prow = &Pb[wave][0];

#pragma unroll 1
  for (int cc = 0; cc < 8; cc++) {
    // 4 mask words (c = cc*4 .. cc*4+3) for each of this lane's 4 q-rows
    uint4 mr[4];
#pragma unroll
    for (int r = 0; r < 4; r++)
      mr[r] = *(const uint4*)&Mw[(row0 + r) * 36 + cc * 4];

#pragma unroll
    for (int ci = 0; ci < 4; ci++) {
      int c = cc * 4 + ci;
      bf16x8 bk0 = *(const bf16x8*)&Ks[(c * 32 + n16) * 8];
      bf16x8 bk1 = *(const bf16x8*)&Ks[(c * 32 + 16 + n16) * 8];
      floatx4 sc0 = __builtin_amdgcn_mfma_f32_16x16x32_bf16(aq, bk0, zero, 0, 0, 0);
      floatx4 sc1 = __builtin_amdgcn_mfma_f32_16x16x32_bf16(aq, bk1, zero, 0, 0, 0);

#pragma unroll
      for (int r = 0; r < 4; r++) {
        uint mw = (ci == 0) ? mr[r].x : (ci == 1) ? mr[r].y
                : (ci == 2) ? mr[r].z : mr[r].w;
        uint tt = mw >> n16;
        uint mexp = (tt & 0x10001u) * 0xFFFFu;   // bit->halfword mask
        float p0 = exp2f(fminf(sc0[r], 15.f));
        float p1 = exp2f(fminf(sc1[r], 15.f));
        uint pw = __builtin_bit_cast(uint, __builtin_amdgcn_cvt_pkrtz(p0, p1));
        pw = (mexp & 0x3C003C00u) | (~mexp & pw);  // masked -> fp16 1.0
        prow[(quad * 4 + r) * 20 + n16] = pw;
      }

      half8 ap = *(const half8*)((const ushort*)prow + n16 * 40 + quad * 8);
      int dd = (n16 < 9) ? n16 : 8;
      half8 bv = *(const half8*)&Vt[dd * 1032 + c * 32 + quad * 8];
      acc = __builtin_amdgcn_mfma_f32_16x16x32_f16(ap, bv, acc, 0, 0, 0);
    }
  }

  // normalize: denominator sits in col 8 of each row
#pragma unroll
  for (int r = 0; r < 4; r++) {
    float dnm = __shfl(acc[r], (lane & 48) | 8, 64);
    if (n16 < 8) {
      int qg = q0 + wave * 16 + quad * 4 + r;
      A[((size_t)(b * S + qg)) * NJ + h * 8 + n16] = acc[r] / dnm;
    }
  }
}

// ---------------------------------------------------------------------------
// K3: out = A@Wo + bo + residual, then LayerNorm. grid BS/8, block 256.
__global__ __launch_bounds__(256) void out_ln_kernel(
    const float* __restrict__ A, const float* __restrict__ Wo,
    const float* __restrict__ bo, const float* __restrict__ qin,
    const float* __restrict__ lnw, const float* __restrict__ lnb,
    float* __restrict__ out) {
  int r0 = blockIdx.x * 8;
  int t = threadIdx.x;
  __shared__ float As[8 * NJ];
#pragma unroll
  for (int i = t; i < 8 * NJ; i += 256) As[i] = A[(size_t)r0 * NJ + i];
  __syncthreads();

  int c0 = t, c1 = t + 256;
  float acc0[8], acc1[8];
#pragma unroll
  for (int r = 0; r < 8; r++) { acc0[r] = 0.f; acc1[r] = 0.f; }

#pragma unroll 4
  for (int j = 0; j < NJ; j++) {
    float w0 = Wo[(size_t)j * DM + c0];
    float w1 = Wo[(size_t)j * DM + c1];
#pragma unroll
    for (int r = 0; r < 8; r++) {
      float a = As[r * NJ + j];
      acc0[r] += a * w0;
      acc1[r] += a * w1;
    }
  }

  float b0 = bo[c0], b1 = bo[c1];
  float y0[8], y1[8], ssum[8], sq[8];
#pragma unroll
  for (int r = 0; r < 8; r++) {
    y0[r] = acc0[r] + b0 + qin[(size_t)(r0 + r) * DM + c0];
    y1[r] = acc1[r] + b1 + qin[(size_t)(r0 + r) * DM + c1];
    ssum[r] = y0[r] + y1[r];
    sq[r] = y0[r] * y0[r] + y1[r] * y1[r];
  }

  int wave = t >> 6, lane = t & 63;
  __shared__ float reds[4][8], redq[4][8];
#pragma unroll
  for (int r = 0; r < 8; r++) {
    float s = ssum[r], qq = sq[r];
#pragma unroll
    for (int off = 32; off > 0; off >>= 1) {
      s += __shfl_xor(s, off, 64);
      qq += __shfl_xor(qq, off, 64);
    }
    if (lane == 0) { reds[wave][r] = s; redq[wave][r] = qq; }
  }
  __syncthreads();

  float lw0 = lnw[c0], lw1 = lnw[c1], lb0 = lnb[c0], lb1 = lnb[c1];
#pragma unroll
  for (int r = 0; r < 8; r++) {
    float s = (reds[0][r] + reds[1][r]) + (reds[2][r] + reds[3][r]);
    float qq = (redq[0][r] + redq[1][r]) + (redq[2][r] + redq[3][r]);
    float mu = s * (1.f / 512.f);
    float var = qq * (1.f / 512.f) - mu * mu;
    float rstd = rsqrtf(var + 1e-5f);
    out[(size_t)(r0 + r) * DM + c0] = (y0[r] - mu) * rstd * lw0 + lb0;
    out[(size_t)(r0 + r) * DM + c1] = (y1[r] - mu) * rstd * lw1 + lb1;
  }
}

// ---------------------------------------------------------------------------
extern "C" void kernel_launch(void* const* d_in, const int* in_sizes, int n_in,
                              void* d_out, int out_size, void* d_ws,
                              size_t ws_size, hipStream_t stream) {
  const float* q_in = (const float*)d_in[0];
  const float* k_in = (const float*)d_in[1];
  const float* v_in = (const float*)d_in[2];
  const int* mask = (const int*)d_in[3];
  const float* Wq = (const float*)d_in[4];
  const float* bq = (const float*)d_in[5];
  const float* Wk = (const float*)d_in[6];
  const float* bk = (const float*)d_in[7];
  const float* Wv = (const float*)d_in[8];
  const float* bv = (const float*)d_in[9];
  const float* Wo = (const float*)d_in[10];
  const float* bo = (const float*)d_in[11];
  const float* lnw = (const float*)d_in[12];
  const float* lnb = (const float*)d_in[13];
  float* out = (float*)d_out;

  constexpr size_t QKV = (size_t)B * H * S * DK;  // 786432 elements each
  ushort* base = (ushort*)d_ws;
  ushort* Qw = base;
  ushort* Kw = base + QKV;
  ushort* Vw = base + 2 * QKV;            // 3*QKV ushorts = 4.5 MB
  float* Aw = (float*)(base + 3 * QKV);   // BS*48 floats = 3 MB
  unsigned long long* bits = (unsigned long long*)(Aw + (size_t)BS * NJ);  // 2 MB
  ushort* Wb = (ushort*)(bits + (size_t)BS * 16);  // 3*24576 bf16

  maskbits_kernel<<<BS / 4, 256, 0, stream>>>(mask, bits);
  wprep_kernel<<<3, 256, 0, stream>>>(Wq, Wk, Wv, Wb);
  proj_kernel<<<dim3(BS / 64, 3), 256, 0, stream>>>(
      q_in, k_in, v_in, Wb, bq, bk, bv, Qw, Kw, Vw);
  attn_kernel<<<(B * H * S) / 64, 256, 0, stream>>>(
      Qw, Kw, Vw, (const uint*)bits, Aw);
  out_ln_kernel<<<BS / 8, 256, 0, stream>>>(Aw, Wo, bo, q_in, lnw, lnb, out);
}

// Round 6
// 306.798 us; speedup vs baseline: 1.9585x; 1.0118x over previous
//
#include <hip/hip_runtime.h>

// Problem constants
constexpr int B = 16;
constexpr int S = 1024;
constexpr int DM = 512;        // D_MODEL
constexpr int H = 6;           // HEADS
constexpr int DK = 8;          // D_K == D_V
constexpr int NJ = H * DK;     // 48 projection cols per matrix
constexpr int BS = B * S;      // 16384 rows
constexpr int WB_ELEMS = 16 * NJ * 32;  // 24576 ushorts per matrix (B-frag order)

typedef __attribute__((ext_vector_type(8))) short bf16x8;
typedef __attribute__((ext_vector_type(8))) _Float16 half8;
typedef __attribute__((ext_vector_type(4))) float floatx4;

// exp2-domain: p = exp(score) = exp2(score*log2e); QSCALE folds 1/sqrt(8)*log2e
#define LOG2E 1.4426950408889634f
#define QSCALE (0.35355339059327373f * LOG2E)

__device__ inline ushort f2bf(float f) {
  unsigned int u = __builtin_bit_cast(unsigned int, f);
  return (ushort)((u + 0x7FFFu + ((u >> 16) & 1u)) >> 16);
}

// ---------------------------------------------------------------------------
// K0: mask int32 [B,S,S] -> bitmask [B*S, 32] uint32 (bit set => fill 1e-9)
__global__ __launch_bounds__(256) void maskbits_kernel(
    const int* __restrict__ mask, unsigned long long* __restrict__ bits) {
  int wave = threadIdx.x >> 6, lane = threadIdx.x & 63;
  int row = blockIdx.x * 4 + wave;            // [0, B*S)
  const int* mrow = mask + (size_t)row * S;
  unsigned long long* brow = bits + (size_t)row * 16;
#pragma unroll
  for (int c = 0; c < 16; c++) {
    int v = mrow[c * 64 + lane];
    unsigned long long bal = __ballot(v != 0);
    if (lane == 0) brow[c] = bal;
  }
}

// ---------------------------------------------------------------------------
// K0b: W prep — fp32 [512][48] -> bf16 B-frag-ordered tiles:
// Wb[m][(kc*48 + n)*32 + kj] = bf16(W[kc*32+kj][n]);  kc=0..15, kj=0..31
__global__ __launch_bounds__(256) void wprep_kernel(
    const float* __restrict__ Wq, const float* __restrict__ Wk,
    const float* __restrict__ Wv, ushort* __restrict__ Wb) {
  int m = blockIdx.x;
  const float* W = (m == 0) ? Wq : (m == 1) ? Wk : Wv;
  ushort* dst = Wb + (size_t)m * WB_ELEMS;
  for (int e = threadIdx.x; e < WB_ELEMS; e += 256) {
    int kc = e / 1536;
    int rem = e - kc * 1536;
    int n = rem >> 5, kj = rem & 31;
    dst[e] = f2bf(W[(size_t)(kc * 32 + kj) * NJ + n]);
  }
}

// ---------------------------------------------------------------------------
// K1: projections via bf16 MFMA. grid (BS/64, 3), block 256 (4 waves).
// W staged once in LDS (B-frag order); X A-frags straight from global.
// Q/K out bf16 (Q pre-scaled by QSCALE incl. log2e); V out fp16.
__global__ __launch_bounds__(256) void proj_kernel(
    const float* __restrict__ q_in, const float* __restrict__ k_in,
    const float* __restrict__ v_in, const ushort* __restrict__ Wb,
    const float* __restrict__ bq, const float* __restrict__ bk,
    const float* __restrict__ bv,
    ushort* __restrict__ Qo, ushort* __restrict__ Ko, ushort* __restrict__ Vo) {
  int m = blockIdx.y;
  const float* x    = (m == 0) ? q_in : (m == 1) ? k_in : v_in;
  const float* bias = (m == 0) ? bq   : (m == 1) ? bk   : bv;
  ushort* out       = (m == 0) ? Qo   : (m == 1) ? Ko   : Vo;
  float oscale      = (m == 0) ? QSCALE : 1.0f;
  const ushort* Wg  = Wb + (size_t)m * WB_ELEMS;

  __shared__ ushort Wl[WB_ELEMS];   // 48 KB

  int t = threadIdx.x;
  {
    const uint4* src = (const uint4*)Wg;
    uint4* dst = (uint4*)Wl;
#pragma unroll
    for (int i = 0; i < 12; i++) dst[t + i * 256] = src[t + i * 256];
  }

  int r0 = blockIdx.x * 64;
  int wave = t >> 6, lane = t & 63;
  int n16 = lane & 15, quad = lane >> 4;
  const float* xrow = x + (size_t)(r0 + wave * 16 + n16) * DM + quad * 8;

  floatx4 acc0 = {0.f, 0.f, 0.f, 0.f};
  floatx4 acc1 = {0.f, 0.f, 0.f, 0.f};
  floatx4 acc2 = {0.f, 0.f, 0.f, 0.f};

  __syncthreads();

#pragma unroll 4
  for (int kc = 0; kc < 16; kc++) {
    float4 xa = *(const float4*)(xrow + kc * 32);
    float4 xb = *(const float4*)(xrow + kc * 32 + 4);
    bf16x8 a;
    a[0] = (short)f2bf(xa.x); a[1] = (short)f2bf(xa.y);
    a[2] = (short)f2bf(xa.z); a[3] = (short)f2bf(xa.w);
    a[4] = (short)f2bf(xb.x); a[5] = (short)f2bf(xb.y);
    a[6] = (short)f2bf(xb.z); a[7] = (short)f2bf(xb.w);
    const ushort* wbase = &Wl[(kc * 48 + n16) * 32 + quad * 8];
    bf16x8 b0 = *(const bf16x8*)(wbase);
    bf16x8 b1 = *(const bf16x8*)(wbase + 16 * 32);
    bf16x8 b2 = *(const bf16x8*)(wbase + 32 * 32);
    acc0 = __builtin_amdgcn_mfma_f32_16x16x32_bf16(a, b0, acc0, 0, 0, 0);
    acc1 = __builtin_amdgcn_mfma_f32_16x16x32_bf16(a, b1, acc1, 0, 0, 0);
    acc2 = __builtin_amdgcn_mfma_f32_16x16x32_bf16(a, b2, acc2, 0, 0, 0);
  }

  // epilogue: C/D layout col=lane&15, row=quad*4+reg
  int baseR = r0 + wave * 16 + quad * 4;
#pragma unroll
  for (int j = 0; j < 3; j++) {
    floatx4 a = (j == 0) ? acc0 : (j == 1) ? acc1 : acc2;
    int n = j * 16 + n16;
    float bn = bias[n];
    int h = n >> 3, d = n & 7;
#pragma unroll
    for (int r = 0; r < 4; r++) {
      int R = baseR + r;
      int b = R >> 10, s = R & 1023;
      float fv = (a[r] + bn) * oscale;
      ushort val = (m == 2) ? __builtin_bit_cast(ushort, (_Float16)fv)
                            : f2bf(fv);
      out[(((size_t)(b * H + h)) * S + s) * 8 + d] = val;
    }
  }
}

// ---------------------------------------------------------------------------
// K2: MFMA attention. grid 1536 (B*H*S/64), block 256 (4 waves).
// K B-frags + mask words read directly from global (L2-hot, prefetchable);
// only Vt (transposed V + ones row) and the P tile live in LDS (23.2 KB ->
// ~5 blocks/CU). QK^T bf16, P fp16 via cvt_pkrtz + bit-trick mask fill,
// PV fp16 MFMA with ones-column denominator.
__global__ __launch_bounds__(256) void attn_kernel(
    const ushort* __restrict__ Qg, const ushort* __restrict__ Kg,
    const ushort* __restrict__ Vg /* fp16 */,
    const uint* __restrict__ bits32, float* __restrict__ A) {
  int bh = blockIdx.x >> 4;
  int qt = blockIdx.x & 15;
  int b = bh / H, h = bh % H;
  int q0 = qt * 64;

  __shared__ ushort Vt[9 * 1032];        // 18.1 KB, fp16 [d(+ones)][pos]
  __shared__ uint Pb[4][16 * 20];        // 5 KB, per-wave fp16 P tile

  int t = threadIdx.x;
  int wave = t >> 6, lane = t & 63;
  int quad = lane >> 4, n16 = lane & 15;

  const ushort* Kbase = Kg + (size_t)bh * S * 8;
  const ushort* Vbase = Vg + (size_t)bh * S * 8;

  // Q A-frag: quad 0 holds d=0..7, other quads zero (kills padded K-range)
  bf16x8 aq = {0, 0, 0, 0, 0, 0, 0, 0};
  if (quad == 0)
    aq = *(const bf16x8*)&Qg[((size_t)bh * S + q0 + wave * 16 + n16) * 8];

  // ---- stage Vt (transposed + key-permuted) ----
#pragma unroll
  for (int i = 0; i < 8; i++) {
    int e = t + i * 256;
    int key = e >> 1, db = (e & 1) << 2;
    ushort4 v = *(const ushort4*)&Vbase[key * 8 + db];
    int g = (key & ~31) + 2 * (key & 15) + ((key >> 4) & 1);
    Vt[(db + 0) * 1032 + g] = v.x;
    Vt[(db + 1) * 1032 + g] = v.y;
    Vt[(db + 2) * 1032 + g] = v.z;
    Vt[(db + 3) * 1032 + g] = v.w;
  }
#pragma unroll
  for (int i = 0; i < 4; i++) Vt[8 * 1032 + t + i * 256] = 0x3C00;  // fp16 1.0
  __syncthreads();

  floatx4 acc = {0.f, 0.f, 0.f, 0.f};
  const floatx4 zero = {0.f, 0.f, 0.f, 0.f};
  int row0 = wave * 16 + quad * 4;
  uint* prow = &Pb[wave][0];
  // this lane's 4 query-rows' mask words
  const uint* mbase = bits32 + ((size_t)(b * S + q0 + row0)) * 32;

#pragma unroll 1
  for (int cc = 0; cc < 8; cc++) {
    uint4 mr[4];
#pragma unroll
    for (int r = 0; r < 4; r++)
      mr[r] = *(const uint4*)(mbase + r * 32 + cc * 4);

#pragma unroll
    for (int ci = 0; ci < 4; ci++) {
      int c = cc * 4 + ci;
      bf16x8 bk0 = *(const bf16x8*)&Kbase[(size_t)(c * 32 + n16) * 8];
      bf16x8 bk1 = *(const bf16x8*)&Kbase[(size_t)(c * 32 + 16 + n16) * 8];
      floatx4 sc0 = __builtin_amdgcn_mfma_f32_16x16x32_bf16(aq, bk0, zero, 0, 0, 0);
      floatx4 sc1 = __builtin_amdgcn_mfma_f32_16x16x32_bf16(aq, bk1, zero, 0, 0, 0);

#pragma unroll
      for (int r = 0; r < 4; r++) {
        uint mw = (ci == 0) ? mr[r].x : (ci == 1) ? mr[r].y
                : (ci == 2) ? mr[r].z : mr[r].w;
        uint tt = mw >> n16;
        uint mexp = (tt & 0x10001u) * 0xFFFFu;   // bit->halfword mask
        float p0 = exp2f(fminf(sc0[r], 15.f));
        float p1 = exp2f(fminf(sc1[r], 15.f));
        uint pw = __builtin_bit_cast(uint, __builtin_amdgcn_cvt_pkrtz(p0, p1));
        pw = (mexp & 0x3C003C00u) | (~mexp & pw);  // masked -> fp16 1.0
        prow[(quad * 4 + r) * 20 + n16] = pw;
      }

      half8 ap = *(const half8*)((const ushort*)prow + n16 * 40 + quad * 8);
      int dd = (n16 < 9) ? n16 : 8;
      half8 bv = *(const half8*)&Vt[dd * 1032 + c * 32 + quad * 8];
      acc = __builtin_amdgcn_mfma_f32_16x16x32_f16(ap, bv, acc, 0, 0, 0);
    }
  }

  // normalize: denominator sits in col 8 of each row
#pragma unroll
  for (int r = 0; r < 4; r++) {
    float dnm = __shfl(acc[r], (lane & 48) | 8, 64);
    if (n16 < 8) {
      int qg = q0 + wave * 16 + quad * 4 + r;
      A[((size_t)(b * S + qg)) * NJ + h * 8 + n16] = acc[r] / dnm;
    }
  }
}

// ---------------------------------------------------------------------------
// K3: out = A@Wo + bo + residual, then LayerNorm. grid BS/8, block 256.
__global__ __launch_bounds__(256) void out_ln_kernel(
    const float* __restrict__ A, const float* __restrict__ Wo,
    const float* __restrict__ bo, const float* __restrict__ qin,
    const float* __restrict__ lnw, const float* __restrict__ lnb,
    float* __restrict__ out) {
  int r0 = blockIdx.x * 8;
  int t = threadIdx.x;
  __shared__ float As[8 * NJ];
#pragma unroll
  for (int i = t; i < 8 * NJ; i += 256) As[i] = A[(size_t)r0 * NJ + i];
  __syncthreads();

  int c0 = t, c1 = t + 256;
  float acc0[8], acc1[8];
#pragma unroll
  for (int r = 0; r < 8; r++) { acc0[r] = 0.f; acc1[r] = 0.f; }

#pragma unroll 4
  for (int j = 0; j < NJ; j++) {
    float w0 = Wo[(size_t)j * DM + c0];
    float w1 = Wo[(size_t)j * DM + c1];
#pragma unroll
    for (int r = 0; r < 8; r++) {
      float a = As[r * NJ + j];
      acc0[r] += a * w0;
      acc1[r] += a * w1;
    }
  }

  float b0 = bo[c0], b1 = bo[c1];
  float y0[8], y1[8], ssum[8], sq[8];
#pragma unroll
  for (int r = 0; r < 8; r++) {
    y0[r] = acc0[r] + b0 + qin[(size_t)(r0 + r) * DM + c0];
    y1[r] = acc1[r] + b1 + qin[(size_t)(r0 + r) * DM + c1];
    ssum[r] = y0[r] + y1[r];
    sq[r] = y0[r] * y0[r] + y1[r] * y1[r];
  }

  int wave = t >> 6, lane = t & 63;
  __shared__ float reds[4][8], redq[4][8];
#pragma unroll
  for (int r = 0; r < 8; r++) {
    float s = ssum[r], qq = sq[r];
#pragma unroll
    for (int off = 32; off > 0; off >>= 1) {
      s += __shfl_xor(s, off, 64);
      qq += __shfl_xor(qq, off, 64);
    }
    if (lane == 0) { reds[wave][r] = s; redq[wave][r] = qq; }
  }
  __syncthreads();

  float lw0 = lnw[c0], lw1 = lnw[c1], lb0 = lnb[c0], lb1 = lnb[c1];
#pragma unroll
  for (int r = 0; r < 8; r++) {
    float s = (reds[0][r] + reds[1][r]) + (reds[2][r] + reds[3][r]);
    float qq = (redq[0][r] + redq[1][r]) + (redq[2][r] + redq[3][r]);
    float mu = s * (1.f / 512.f);
    float var = qq * (1.f / 512.f) - mu * mu;
    float rstd = rsqrtf(var + 1e-5f);
    out[(size_t)(r0 + r) * DM + c0] = (y0[r] - mu) * rstd * lw0 + lb0;
    out[(size_t)(r0 + r) * DM + c1] = (y1[r] - mu) * rstd * lw1 + lb1;
  }
}

// ---------------------------------------------------------------------------
extern "C" void kernel_launch(void* const* d_in, const int* in_sizes, int n_in,
                              void* d_out, int out_size, void* d_ws,
                              size_t ws_size, hipStream_t stream) {
  const float* q_in = (const float*)d_in[0];
  const float* k_in = (const float*)d_in[1];
  const float* v_in = (const float*)d_in[2];
  const int* mask = (const int*)d_in[3];
  const float* Wq = (const float*)d_in[4];
  const float* bq = (const float*)d_in[5];
  const float* Wk = (const float*)d_in[6];
  const float* bk = (const float*)d_in[7];
  const float* Wv = (const float*)d_in[8];
  const float* bv = (const float*)d_in[9];
  const float* Wo = (const float*)d_in[10];
  const float* bo = (const float*)d_in[11];
  const float* lnw = (const float*)d_in[12];
  const float* lnb = (const float*)d_in[13];
  float* out = (float*)d_out;

  constexpr size_t QKV = (size_t)B * H * S * DK;  // 786432 elements each
  ushort* base = (ushort*)d_ws;
  ushort* Qw = base;
  ushort* Kw = base + QKV;
  ushort* Vw = base + 2 * QKV;            // 3*QKV ushorts = 4.5 MB
  float* Aw = (float*)(base + 3 * QKV);   // BS*48 floats = 3 MB
  unsigned long long* bits = (unsigned long long*)(Aw + (size_t)BS * NJ);  // 2 MB
  ushort* Wb = (ushort*)(bits + (size_t)BS * 16);  // 3*24576 bf16

  maskbits_kernel<<<BS / 4, 256, 0, stream>>>(mask, bits);
  wprep_kernel<<<3, 256, 0, stream>>>(Wq, Wk, Wv, Wb);
  proj_kernel<<<dim3(BS / 64, 3), 256, 0, stream>>>(
      q_in, k_in, v_in, Wb, bq, bk, bv, Qw, Kw, Vw);
  attn_kernel<<<(B * H * S) / 64, 256, 0, stream>>>(
      Qw, Kw, Vw, (const uint*)bits, Aw);
  out_ln_kernel<<<BS / 8, 256, 0, stream>>>(Aw, Wo, bo, q_in, lnw, lnb, out);
}